// Round 5
// baseline (9569.083 us; speedup 1.0000x reference)
//
#include <hip/hip_runtime.h>
#include <math.h>

// ---- problem constants ----
#define BB 128
#define LL 200
#define DM 320
#define RTOT (BB*LL)          // 25600
#define NCH 129
#define DIN 640               // 2*DM
#define HM 20                 // mamba heads
#define PP 32                 // headdim
#define NN 32                 // d_state
#define CDIM 704              // DIN + 2*NN
#define DPROJ 1364            // 2*DIN + 2*NN + HM
#define NH 16                 // attn heads
#define HD 20                 // DM/NH
#define ATTN_SCALE 0.22360679774997896f  // 1/sqrt(20)
#define KCONV 160             // 129 zero-padded to multiple of 32

// batch chunking (sequences independent)
#define CH 32
#define NCHUNK 4
#define RC (CH*LL)            // 6400 rows (phase A/C chunk)
#define CHB 16
#define NCHUNKB 8
#define RCB (CHB*LL)          // 3200 rows (phase B chunk)

typedef unsigned short ushort;
typedef __attribute__((ext_vector_type(8))) short v8s;
typedef __attribute__((ext_vector_type(4))) float v4f;

static __device__ __forceinline__ float sigmoidf_(float x){ return 1.f/(1.f+__expf(-x)); }
static __device__ __forceinline__ float geluf_(float x){ return 0.5f*x*(1.f+erff(x*0.70710678118654752f)); }
static __device__ __forceinline__ ushort f2bf(float f){
  unsigned u = __float_as_uint(f);
  u = (u + 0x7FFFu + ((u>>16)&1u)) >> 16;
  return (ushort)u;
}
static __device__ __forceinline__ float bf2f(ushort h){ return __uint_as_float(((unsigned)h)<<16); }
// exact 3-way split: v == h + m + l (bit-exact for fp32)
static __device__ __forceinline__ void split3(float v, ushort* h, ushort* m, ushort* l){
  ushort hh = f2bf(v);
  float r1 = v - bf2f(hh);
  ushort mm = f2bf(r1);
  float r2 = r1 - bf2f(mm);
  *h = hh; *m = mm; *l = f2bf(r2);
}

// ================= bf16x6 MFMA GEMM (fp32-accurate via exact 3-way split) =================
// C[M,N] = act(A[M,K] @ W[N,K]^T + bias) (+C if accum)
// A,W pre-split into bf16 h/m/l (exact). M mult of 128, K mult of 32, N masked.
// grid: (ceil(N/128), M/128), 256 threads (4 waves, 2x2 of 64x64 wave tiles)
__global__ __launch_bounds__(256) void k_mgemm(
    const ushort* __restrict__ AH, const ushort* __restrict__ AM, const ushort* __restrict__ AL,
    const ushort* __restrict__ WH, const ushort* __restrict__ WM, const ushort* __restrict__ WL,
    const float* __restrict__ bias,
    float* __restrict__ outF, ushort* __restrict__ outH, ushort* __restrict__ outM, ushort* __restrict__ outL,
    int M, int N, int K, int act, int accum){
  __shared__ ushort sA[3][128*32];
  __shared__ ushort sW[3][128*32];
  int tid = threadIdx.x;
  int wid = tid>>6, lane = tid&63;
  int quad = lane>>4, col = lane&15;
  int m0 = blockIdx.y*128, n0 = blockIdx.x*128;
  int wm = (wid&1)*64, wn = (wid>>1)*64;
  v4f acc[4][4];
  #pragma unroll
  for (int i=0;i<4;i++)
    #pragma unroll
    for (int j=0;j<4;j++) acc[i][j] = (v4f)(0.f);

  // staging: v8s groups g in [0,512): row=g>>2, kcol=(g&3)*8; thread does g0=tid, g1=tid+256
  int r0 = tid>>2, kc0 = (tid&3)<<3;
  int r1 = r0 + 64, kc1 = kc0;
  int wrow0 = n0+r0; if (wrow0 > N-1) wrow0 = N-1;
  int wrow1 = n0+r1; if (wrow1 > N-1) wrow1 = N-1;
  const ushort* pA[3] = {AH, AM, AL};
  const ushort* pW[3] = {WH, WM, WL};
  size_t aoff0 = (size_t)(m0+r0)*K + kc0;
  size_t aoff1 = (size_t)(m0+r1)*K + kc1;
  size_t woff0 = (size_t)wrow0*K + kc0;
  size_t woff1 = (size_t)wrow1*K + kc1;
  int so0 = r0*32 + kc0, so1 = r1*32 + kc1;

  for (int kb = 0; kb < K; kb += 32) {
    #pragma unroll
    for (int s=0;s<3;s++){
      v8s va0 = *(const v8s*)(pA[s]+aoff0+kb);
      v8s va1 = *(const v8s*)(pA[s]+aoff1+kb);
      v8s vw0 = *(const v8s*)(pW[s]+woff0+kb);
      v8s vw1 = *(const v8s*)(pW[s]+woff1+kb);
      *(v8s*)&sA[s][so0]=va0; *(v8s*)&sA[s][so1]=va1;
      *(v8s*)&sW[s][so0]=vw0; *(v8s*)&sW[s][so1]=vw1;
    }
    __syncthreads();
    v8s af[3][4];
    #pragma unroll
    for (int i=0;i<4;i++){
      int ro = (wm+16*i+col)*32 + quad*8;
      af[0][i] = *(const v8s*)&sA[0][ro];
      af[1][i] = *(const v8s*)&sA[1][ro];
      af[2][i] = *(const v8s*)&sA[2][ro];
    }
    #pragma unroll
    for (int j=0;j<4;j++){
      int ro = (wn+16*j+col)*32 + quad*8;
      v8s b0 = *(const v8s*)&sW[0][ro];
      v8s b1 = *(const v8s*)&sW[1][ro];
      v8s b2 = *(const v8s*)&sW[2][ro];
      #pragma unroll
      for (int i=0;i<4;i++){
        // smallest-first accumulate; dropped terms are <= 2^-26
        acc[i][j] = __builtin_amdgcn_mfma_f32_16x16x32_bf16(af[2][i], b0, acc[i][j], 0,0,0); // al*bh
        acc[i][j] = __builtin_amdgcn_mfma_f32_16x16x32_bf16(af[1][i], b1, acc[i][j], 0,0,0); // am*bm
        acc[i][j] = __builtin_amdgcn_mfma_f32_16x16x32_bf16(af[0][i], b2, acc[i][j], 0,0,0); // ah*bl
        acc[i][j] = __builtin_amdgcn_mfma_f32_16x16x32_bf16(af[1][i], b0, acc[i][j], 0,0,0); // am*bh
        acc[i][j] = __builtin_amdgcn_mfma_f32_16x16x32_bf16(af[0][i], b1, acc[i][j], 0,0,0); // ah*bm
        acc[i][j] = __builtin_amdgcn_mfma_f32_16x16x32_bf16(af[0][i], b0, acc[i][j], 0,0,0); // ah*bh
      }
    }
    __syncthreads();
  }
  // epilogue: C/D layout col=lane&15, row=quad*4+reg
  #pragma unroll
  for (int i=0;i<4;i++){
    int mb = m0 + wm + 16*i + quad*4;
    #pragma unroll
    for (int j=0;j<4;j++){
      int n = n0 + wn + 16*j + col;
      if (n >= N) continue;
      float bv = bias ? bias[n] : 0.f;
      #pragma unroll
      for (int r=0;r<4;r++){
        float v = acc[i][j][r] + bv;
        if (act == 1) v = geluf_(v);
        else if (act == 2) v = tanhf(v);
        size_t off = (size_t)(mb+r)*N + n;
        if (accum) v += outF[off];
        if (outF) outF[off] = v;
        if (outH) split3(v, outH+off, outM+off, outL+off);
      }
    }
  }
}

// ================= fp32 GEMM (tiny: head1 only) =================
#define BM 128
#define BN 64
#define BKK 16
__global__ __launch_bounds__(256) void k_gemm(const float* __restrict__ A, const float* __restrict__ W,
    const float* __restrict__ bias, float* __restrict__ C, int M, int N, int K, int act, int accum){
  __shared__ float As[BKK][BM+4];
  __shared__ float Ws[BKK][BN+4];
  int tid = threadIdx.x;
  int m0 = blockIdx.y*BM, n0 = blockIdx.x*BN;
  int tx = tid & 15, ty = tid >> 4;
  float acc[8][4];
  #pragma unroll
  for (int i=0;i<8;i++)
    #pragma unroll
    for (int j=0;j<4;j++) acc[i][j]=0.f;
  for (int k0 = 0; k0 < K; k0 += BKK) {
    int r = tid >> 2, c4 = (tid & 3) << 2;
    #pragma unroll
    for (int hfl = 0; hfl < 2; hfl++) {
      int rr = r + hfl*64;
      float4 v = make_float4(0.f,0.f,0.f,0.f);
      if (m0 + rr < M && k0 + c4 < K)
        v = *(const float4*)(A + (size_t)(m0+rr)*K + k0 + c4);
      As[c4+0][rr]=v.x; As[c4+1][rr]=v.y; As[c4+2][rr]=v.z; As[c4+3][rr]=v.w;
    }
    {
      int n = tid >> 2;
      float4 v = make_float4(0.f,0.f,0.f,0.f);
      if (n0 + n < N && k0 + c4 < K)
        v = *(const float4*)(W + (size_t)(n0+n)*K + k0 + c4);
      Ws[c4+0][n]=v.x; Ws[c4+1][n]=v.y; Ws[c4+2][n]=v.z; Ws[c4+3][n]=v.w;
    }
    __syncthreads();
    #pragma unroll
    for (int kk = 0; kk < BKK; kk++) {
      float af[8], bf[4];
      float4 a0 = *(const float4*)&As[kk][ty*8];
      float4 a1 = *(const float4*)&As[kk][ty*8+4];
      af[0]=a0.x; af[1]=a0.y; af[2]=a0.z; af[3]=a0.w;
      af[4]=a1.x; af[5]=a1.y; af[6]=a1.z; af[7]=a1.w;
      float4 b0 = *(const float4*)&Ws[kk][tx*4];
      bf[0]=b0.x; bf[1]=b0.y; bf[2]=b0.z; bf[3]=b0.w;
      #pragma unroll
      for (int i=0;i<8;i++)
        #pragma unroll
        for (int j=0;j<4;j++) acc[i][j] = fmaf(af[i], bf[j], acc[i][j]);
    }
    __syncthreads();
  }
  #pragma unroll
  for (int i=0;i<8;i++){
    int m = m0 + ty*8 + i;
    if (m >= M) continue;
    #pragma unroll
    for (int j=0;j<4;j++){
      int n = n0 + tx*4 + j;
      if (n >= N) continue;
      float v = acc[i][j];
      if (bias) v += bias[n];
      if (act == 1) v = geluf_(v);
      else if (act == 2) v = tanhf(v);
      size_t off = (size_t)m*N + n;
      if (accum) v += C[off];
      C[off] = v;
    }
  }
}

// ================= splits =================
__global__ __launch_bounds__(256) void k_wsplit(const float* __restrict__ src, ushort* __restrict__ hi,
    ushort* __restrict__ mi, ushort* __restrict__ lo, int N, int K, int Kp){
  int idx = blockIdx.x*256 + threadIdx.x;
  if (idx >= N*Kp) return;
  int n = idx / Kp, k = idx - n*Kp;
  float v = (k < K) ? src[(size_t)n*K + k] : 0.f;
  split3(v, hi+idx, mi+idx, lo+idx);
}

__global__ __launch_bounds__(256) void k_split(const float* __restrict__ src, ushort* __restrict__ hi,
    ushort* __restrict__ mi, ushort* __restrict__ lo, int n){
  int idx = blockIdx.x*256 + threadIdx.x;
  if (idx >= n) return;
  split3(src[idx], hi+idx, mi+idx, lo+idx);
}

// transpose+pad+split one chunk of rows: rows [r0g, r0g+RC)
__global__ __launch_bounds__(256) void k_tsplit(const float* __restrict__ x, ushort* __restrict__ hi,
    ushort* __restrict__ mi, ushort* __restrict__ lo, int r0g){
  int idx = blockIdx.x*256 + threadIdx.x;
  if (idx >= RC*KCONV) return;
  int r = idx / KCONV, c = idx - r*KCONV;
  int gr = r0g + r;
  int b = gr / LL, l = gr - b*LL;
  float v = (c < NCH) ? x[((size_t)b*NCH + c)*LL + l] : 0.f;
  split3(v, hi+idx, mi+idx, lo+idx);
}

// ================= LayerNorm (D=320), optional add, outputs fp32 and/or bf16 h/m/l
__global__ __launch_bounds__(256) void k_ln(const float* __restrict__ A, const float* __restrict__ Badd,
    float* __restrict__ Of, ushort* __restrict__ Oh, ushort* __restrict__ Om, ushort* __restrict__ Ol,
    const float* __restrict__ w, const float* __restrict__ b, int nrows){
  int wid = threadIdx.x >> 6, lane = threadIdx.x & 63;
  int row = blockIdx.x*4 + wid;
  if (row >= nrows) return;
  const float* a = A + (size_t)row*DM;
  float x[5]; float s = 0.f;
  #pragma unroll
  for (int j=0;j<5;j++){
    int c = lane + j*64;
    x[j] = a[c];
    if (Badd) x[j] += Badd[(size_t)row*DM + c];
    s += x[j];
  }
  #pragma unroll
  for (int m=1;m<64;m<<=1) s += __shfl_xor(s, m);
  float mean = s * (1.f/DM);
  float vs = 0.f;
  #pragma unroll
  for (int j=0;j<5;j++){ float d = x[j]-mean; vs += d*d; }
  #pragma unroll
  for (int m=1;m<64;m<<=1) vs += __shfl_xor(vs, m);
  float inv = rsqrtf(vs*(1.f/DM) + 1e-5f);
  #pragma unroll
  for (int j=0;j<5;j++){
    int c = lane + j*64;
    float v = (x[j]-mean)*inv*w[c] + b[c];
    size_t off = (size_t)row*DM + c;
    if (Of) Of[off] = v;
    if (Oh) split3(v, Oh+off, Om+off, Ol+off);
  }
}

// fused double-LN: O = LN(LN(A+F)*w2+b2)*w3+b3
__global__ __launch_bounds__(256) void k_ln2x(const float* __restrict__ A, const float* __restrict__ F,
    const float* __restrict__ w2, const float* __restrict__ b2,
    const float* __restrict__ w3, const float* __restrict__ b3,
    float* __restrict__ O, int nrows){
  int wid = threadIdx.x >> 6, lane = threadIdx.x & 63;
  int row = blockIdx.x*4 + wid;
  if (row >= nrows) return;
  float x[5]; float s = 0.f;
  #pragma unroll
  for (int j=0;j<5;j++){
    int c = lane + j*64;
    x[j] = A[(size_t)row*DM + c] + F[(size_t)row*DM + c];
    s += x[j];
  }
  #pragma unroll
  for (int m=1;m<64;m<<=1) s += __shfl_xor(s, m);
  float mean = s * (1.f/DM);
  float vs = 0.f;
  #pragma unroll
  for (int j=0;j<5;j++){ float d = x[j]-mean; vs += d*d; }
  #pragma unroll
  for (int m=1;m<64;m<<=1) vs += __shfl_xor(vs, m);
  float inv = rsqrtf(vs*(1.f/DM) + 1e-5f);
  float s2 = 0.f;
  #pragma unroll
  for (int j=0;j<5;j++){
    int c = lane + j*64;
    x[j] = (x[j]-mean)*inv*w2[c] + b2[c];
    s2 += x[j];
  }
  #pragma unroll
  for (int m=1;m<64;m<<=1) s2 += __shfl_xor(s2, m);
  float mean2 = s2 * (1.f/DM);
  float vs2 = 0.f;
  #pragma unroll
  for (int j=0;j<5;j++){ float d = x[j]-mean2; vs2 += d*d; }
  #pragma unroll
  for (int m=1;m<64;m<<=1) vs2 += __shfl_xor(vs2, m);
  float inv2 = rsqrtf(vs2*(1.f/DM) + 1e-5f);
  #pragma unroll
  for (int j=0;j<5;j++){
    int c = lane + j*64;
    O[(size_t)row*DM + c] = (x[j]-mean2)*inv2*w3[c] + b3[c];
  }
}

// ================= attention pass 1: per (b,h), online softmax -> o (h/m/l), store (m,l)
__global__ __launch_bounds__(256) void k_attn1(const float* __restrict__ qkv,
    ushort* __restrict__ oh, ushort* __restrict__ om, ushort* __restrict__ ol, float* __restrict__ ml){
  __shared__ float Ks[LL*HD];
  __shared__ float Vs[LL*HD];
  int b = blockIdx.x >> 4, h = blockIdx.x & 15;
  int tid = threadIdx.x;
  for (int idx = tid; idx < LL*HD; idx += 256) {
    int r = idx / HD, c = idx - r*HD;
    const float* base = qkv + (size_t)(b*LL+r)*960 + h*HD + c;
    Ks[idx] = base[320];
    Vs[idx] = base[640];
  }
  __syncthreads();
  int q = tid;
  if (q >= LL) return;
  const float* qp = qkv + (size_t)(b*LL+q)*960 + h*HD;
  float qr[HD];
  #pragma unroll
  for (int d4 = 0; d4 < 5; d4++) {
    float4 v = *(const float4*)(qp + d4*4);
    qr[d4*4]=v.x; qr[d4*4+1]=v.y; qr[d4*4+2]=v.z; qr[d4*4+3]=v.w;
  }
  float m = -1e30f, l = 0.f;
  float o[HD];
  #pragma unroll
  for (int d=0; d<HD; d++) o[d]=0.f;
  for (int k = 0; k < LL; k++) {
    float s = 0.f;
    #pragma unroll
    for (int d = 0; d < HD; d++) s = fmaf(qr[d], Ks[k*HD+d], s);
    s *= ATTN_SCALE;
    float nm = fmaxf(m, s);
    float al = __expf(m - nm);
    float p  = __expf(s - nm);
    l = l*al + p;
    #pragma unroll
    for (int d = 0; d < HD; d++) o[d] = fmaf(p, Vs[k*HD+d], o[d]*al);
    m = nm;
  }
  float inv = 1.f/l;
  size_t ob = (size_t)(b*LL+q)*DM + h*HD;
  #pragma unroll
  for (int d = 0; d < HD; d++) {
    split3(o[d]*inv, oh+ob+d, om+ob+d, ol+ob+d);
  }
  size_t mlb = ((size_t)(b*NH+h)*LL + q)*2;
  ml[mlb+0] = m;
  ml[mlb+1] = l;
}

// ================= attention pass 2: head-mean probabilities, tiled 32q x 32k
#define QS 164
__global__ __launch_bounds__(256) void k_attnmean(const float* __restrict__ qkv,
    const float* __restrict__ ml, float* __restrict__ outp){
  __shared__ float Qs[32*QS];
  __shared__ float Ksh[32*QS];
  __shared__ float Ms[NH*32];
  __shared__ float Ls[NH*32];
  int b = blockIdx.z;
  int q0 = blockIdx.y*32, k0 = blockIdx.x*32;
  int tid = threadIdx.x;
  for (int idx = tid; idx < NH*32; idx += 256) {
    int h = idx >> 5, r = idx & 31;
    int q = q0 + r;
    float m = 0.f, li = 1.f;
    if (q < LL) {
      size_t base = ((size_t)(b*NH+h)*LL + q)*2;
      m = ml[base+0];
      li = 1.f/ml[base+1];
    }
    Ms[idx] = m; Ls[idx] = li;
  }
  int tx = tid & 31, ty = tid >> 5;
  float acc[4] = {0.f,0.f,0.f,0.f};
  for (int hc = 0; hc < 2; hc++) {
    __syncthreads();
    for (int idx = tid; idx < 32*160; idx += 256) {
      int r = idx / 160, c = idx - r*160;
      int q = q0 + r, k = k0 + r;
      Qs[r*QS + c]  = (q < LL) ? qkv[(size_t)(b*LL+q)*960 + hc*160 + c] : 0.f;
      Ksh[r*QS + c] = (k < LL) ? qkv[(size_t)(b*LL+k)*960 + 320 + hc*160 + c] : 0.f;
    }
    __syncthreads();
    #pragma unroll
    for (int hh = 0; hh < 8; hh++) {
      int h = hc*8 + hh;
      float kf[HD];
      #pragma unroll
      for (int d4 = 0; d4 < 5; d4++) {
        float4 v = *(const float4*)&Ksh[tx*QS + hh*HD + d4*4];
        kf[d4*4]=v.x; kf[d4*4+1]=v.y; kf[d4*4+2]=v.z; kf[d4*4+3]=v.w;
      }
      #pragma unroll
      for (int j = 0; j < 4; j++) {
        int qr = ty + j*8;
        float s = 0.f;
        #pragma unroll
        for (int d4 = 0; d4 < 5; d4++) {
          float4 v = *(const float4*)&Qs[qr*QS + hh*HD + d4*4];
          s += v.x*kf[d4*4] + v.y*kf[d4*4+1] + v.z*kf[d4*4+2] + v.w*kf[d4*4+3];
        }
        acc[j] += __expf(s*ATTN_SCALE - Ms[h*32 + qr]) * Ls[h*32 + qr];
      }
    }
  }
  #pragma unroll
  for (int j = 0; j < 4; j++) {
    int q = q0 + ty + j*8, k = k0 + tx;
    if (q < LL && k < LL)
      outp[(size_t)(b*LL+q)*LL + k] = acc[j] * (1.f/NH);
  }
}

// ================= causal depthwise conv (width 4) + silu
__global__ __launch_bounds__(256) void k_conv(const float* __restrict__ big, const float* __restrict__ cw,
    const float* __restrict__ cb, float* __restrict__ xc, int nrows){
  int idx = blockIdx.x*256 + threadIdx.x;
  if (idx >= nrows*CDIM) return;
  int row = idx / CDIM, c = idx - row*CDIM;
  int l = row % LL;
  float acc = cb[c];
  #pragma unroll
  for (int k = 0; k < 4; k++) {
    int li = l - 3 + k;
    if (li >= 0) acc = fmaf(big[(size_t)(row-3+k)*DPROJ + 640 + c], cw[c*4+k], acc);
  }
  xc[idx] = acc * sigmoidf_(acc);
}

// ================= selective scan (dt/dA inline); b is chunk-local
__global__ __launch_bounds__(256) void k_scan(const float* __restrict__ xc, const float* __restrict__ big,
    const float* __restrict__ dtb, const float* __restrict__ alog, float* __restrict__ y){
  __shared__ float xs[LL*PP];
  __shared__ float dts[LL];
  __shared__ float das[LL];
  int b = blockIdx.x / HM, h = blockIdx.x - (blockIdx.x/HM)*HM;
  int tid = threadIdx.x;
  for (int idx = tid; idx < LL*PP; idx += 256) {
    int r = idx >> 5, c = idx & 31;
    xs[idx] = xc[(size_t)(b*LL+r)*CDIM + h*PP + c];
  }
  float aexp = __expf(alog[h]);
  float dtbh = dtb[h];
  for (int idx = tid; idx < LL; idx += 256) {
    float raw = big[(size_t)(b*LL+idx)*DPROJ + 1344 + h] + dtbh;
    float sp = (raw > 30.f) ? raw : log1pf(__expf(raw));
    dts[idx] = sp;
    das[idx] = __expf(-aexp * sp);
  }
  __syncthreads();
  int p = tid >> 3, ng = tid & 7, n0 = ng*4;
  float st0=0.f, st1=0.f, st2=0.f, st3=0.f;
  const float* base = xc + (size_t)(b*LL)*CDIM;
  float4 Bc = *(const float4*)(base + 640 + n0);
  float4 Cc = *(const float4*)(base + 672 + n0);
  for (int t = 0; t < LL; t++) {
    float4 Bn = Bc, Cn = Cc;
    if (t < LL-1) {
      Bn = *(const float4*)(base + (size_t)(t+1)*CDIM + 640 + n0);
      Cn = *(const float4*)(base + (size_t)(t+1)*CDIM + 672 + n0);
    }
    float dav = das[t], dtv = dts[t];
    float coef = dtv * xs[t*PP + p];
    st0 = fmaf(coef, Bc.x, st0*dav);
    st1 = fmaf(coef, Bc.y, st1*dav);
    st2 = fmaf(coef, Bc.z, st2*dav);
    st3 = fmaf(coef, Bc.w, st3*dav);
    float part = st0*Cc.x + st1*Cc.y + st2*Cc.z + st3*Cc.w;
    part += __shfl_xor(part, 1);
    part += __shfl_xor(part, 2);
    part += __shfl_xor(part, 4);
    if (ng == 0) y[(size_t)(b*LL+t)*DIN + h*PP + p] = part;
    Bc = Bn; Cc = Cn;
  }
}

// ================= mamba epilogue -> bf16 h/m/l
__global__ __launch_bounds__(256) void k_mpost(const float* __restrict__ y, const float* __restrict__ xc,
    const float* __restrict__ zbuf, const float* __restrict__ Dp, const float* __restrict__ gw,
    ushort* __restrict__ yh, ushort* __restrict__ ym, ushort* __restrict__ yl, int nrows){
  int wid = threadIdx.x >> 6, lane = threadIdx.x & 63;
  int row = blockIdx.x*4 + wid;
  if (row >= nrows) return;
  float v[10]; float ss = 0.f;
  #pragma unroll
  for (int j = 0; j < 10; j++) {
    int c = lane + j*64;
    float ys = y[(size_t)row*DIN + c];
    float xh = xc[(size_t)row*CDIM + c];
    float z  = zbuf[(size_t)row*DPROJ + c];
    float val = (ys + Dp[c>>5]*xh) * (z * sigmoidf_(z));
    v[j] = val; ss += val*val;
  }
  #pragma unroll
  for (int m=1;m<64;m<<=1) ss += __shfl_xor(ss, m);
  float scale = rsqrtf(ss*(1.f/DIN) + 1e-5f);
  #pragma unroll
  for (int j = 0; j < 10; j++) {
    int c = lane + j*64;
    float val = v[j]*scale*gw[c];
    size_t off = (size_t)row*DIN + c;
    split3(val, yh+off, ym+off, yl+off);
  }
}

// ================= pool2
__global__ __launch_bounds__(256) void k_pool2(const float* __restrict__ A, const float* __restrict__ w2,
    const float* __restrict__ b2, float* __restrict__ out, int nrows){
  int row = blockIdx.x*256 + threadIdx.x;
  if (row >= nrows) return;
  float s = b2[0];
  const float* a = A + (size_t)row*80;
  #pragma unroll
  for (int j = 0; j < 80; j++) s = fmaf(a[j], w2[j], s);
  out[row] = s;
}

// ================= softmax over L + attention-pool
__global__ __launch_bounds__(256) void k_pool(const float* __restrict__ logits, const float* __restrict__ h,
    float* __restrict__ a_out, float* __restrict__ pooled){
  __shared__ float red[256];
  __shared__ float as_[LL];
  int b = blockIdx.x, tid = threadIdx.x;
  float v = (tid < LL) ? logits[b*LL + tid] : -1e30f;
  red[tid] = v; __syncthreads();
  for (int s=128; s>0; s>>=1){ if (tid<s) red[tid]=fmaxf(red[tid],red[tid+s]); __syncthreads(); }
  float mx = red[0]; __syncthreads();
  float e = (tid<LL) ? __expf(v - mx) : 0.f;
  red[tid] = e; __syncthreads();
  for (int s=128; s>0; s>>=1){ if (tid<s) red[tid]+=red[tid+s]; __syncthreads(); }
  float inv = 1.f/red[0];
  if (tid < LL){ float av = e*inv; as_[tid]=av; a_out[b*LL+tid]=av; }
  __syncthreads();
  for (int d = tid; d < DM; d += 256) {
    float s = 0.f;
    for (int l=0;l<LL;l++) s = fmaf(h[(size_t)(b*LL+l)*DM + d], as_[l], s);
    pooled[b*DM + d] = s;
  }
}

// ================= head final dot
__global__ __launch_bounds__(128) void k_head2(const float* __restrict__ hr, const float* __restrict__ w2,
    const float* __restrict__ b2, float* __restrict__ out){
  int b = threadIdx.x;
  if (b >= BB) return;
  float s = b2[0];
  const float* a = hr + (size_t)b*160;
  #pragma unroll
  for (int j = 0; j < 160; j++) s = fmaf(a[j], w2[j], s);
  out[b] = s;
}

// ================= host side =================
static inline void mgemm(const ushort* AH, const ushort* AM, const ushort* AL,
    const ushort* WH, const ushort* WM, const ushort* WL,
    const float* bias, float* outF, ushort* outH, ushort* outM, ushort* outL,
    int M, int N, int K, int act, int accum, hipStream_t s){
  hipLaunchKernelGGL(k_mgemm, dim3((N+127)/128, M/128), dim3(256), 0, s,
                     AH, AM, AL, WH, WM, WL, bias, outF, outH, outM, outL, M, N, K, act, accum);
}
static inline void wsplit(const float* src, ushort* hi, ushort* mi, ushort* lo, int N, int K, int Kp, hipStream_t s){
  hipLaunchKernelGGL(k_wsplit, dim3((N*Kp+255)/256), dim3(256), 0, s, src, hi, mi, lo, N, K, Kp);
}

// ---- workspace layout (float offsets), total 30,161,920 fl = 120.6 MB ----
#define F_H      ((size_t)0)               // 8,192,000 fp32 persistent hidden
// weight splits (each array ushort; size in floats = count/2)
#define F_WCONVH ((size_t)8192000)
#define F_WCONVM ((size_t)8217600)
#define F_WCONVL ((size_t)8243200)
#define F_WQKVH  ((size_t)8268800)
#define F_WQKVM  ((size_t)8422400)
#define F_WQKVL  ((size_t)8576000)
#define F_WOUTH  ((size_t)8729600)
#define F_WOUTM  ((size_t)8780800)
#define F_WOUTL  ((size_t)8832000)
#define F_WFF1H  ((size_t)8883200)
#define F_WFF1M  ((size_t)8985600)
#define F_WFF1L  ((size_t)9088000)
#define F_WFF2H  ((size_t)9190400)
#define F_WFF2M  ((size_t)9292800)
#define F_WFF2L  ((size_t)9395200)
#define F_WINH   ((size_t)9497600)
#define F_WINM   ((size_t)10370560)
#define F_WINL   ((size_t)11243520)
#define F_WMOH   ((size_t)12116480)
#define F_WMOM   ((size_t)12526080)
#define F_WMOL   ((size_t)12935680)
#define F_WPQH   ((size_t)13345280)
#define F_WPQM   ((size_t)13498880)
#define F_WPQL   ((size_t)13652480)
#define F_WPOH   ((size_t)13806080)
#define F_WPOM   ((size_t)13857280)
#define F_WPOL   ((size_t)13908480)
#define F_WPLH   ((size_t)13959680)
#define F_WPLM   ((size_t)13972480)
#define F_WPLL   ((size_t)13985280)
#define SB       ((size_t)13998080)
// phase A/C scratch (CH=32, RC=6400)
#define S_XTH  (SB+0)
#define S_XTM  (SB+512000)
#define S_XTL  (SB+1024000)
#define S_HH   (SB+1536000)
#define S_HM   (SB+2560000)
#define S_HL   (SB+3584000)
#define S_TH   (SB+4608000)
#define S_TM   (SB+5632000)
#define S_TL   (SB+6656000)
#define S_QKV  (SB+7680000)        // 6,144,000 fp32
#define S_FF1H (SB+7680000)        // overlays QKV (dead after attnmean)
#define S_FF1M (SB+9728000)
#define S_FF1L (SB+11776000)
#define S_P1   (SB+7680000)        // phase C overlay of QKV
#define S_ML   (SB+13824000)
#define S_DEST (SB+14028800)       // 2,048,000 -> ends 16,076,800
#define S_LOG  (SB+16076800)
#define S_PL   (SB+16102400)
#define S_HR   (SB+16143360)       // ends 16,163,840
// phase B overlay (CHB=16, RCB=3200)
#define S_MTH  (SB+0)
#define S_MTM  (SB+512000)
#define S_MTL  (SB+1024000)
#define S_BIG  (SB+1536000)        // 4,364,800
#define S_XC   (SB+5900800)        // 2,252,800
#define S_YC   (SB+8153600)        // 2,048,000
#define S_YH   (SB+10201600)
#define S_YM   (SB+11225600)
#define S_YL   (SB+12249600)       // ends 13,273,600

// output layout (floats): (out, sp_attn, post_attn, a)
#define O_OUT ((size_t)0)
#define O_A1  ((size_t)128)
#define O_A2  ((size_t)5120128)
#define O_A   ((size_t)10240128)

extern "C" void kernel_launch(void* const* d_in, const int* in_sizes, int n_in,
                              void* d_out, int out_size, void* d_ws, size_t ws_size,
                              hipStream_t stream) {
  const float* x         = (const float*)d_in[0];
  const float* sp_conv_w = (const float*)d_in[1];
  const float* sp_conv_b = (const float*)d_in[2];
  const float* sp_qkv_w  = (const float*)d_in[3];
  const float* sp_qkv_b  = (const float*)d_in[4];
  const float* sp_out_w  = (const float*)d_in[5];
  const float* sp_out_b  = (const float*)d_in[6];
  const float* sp_ln1_w  = (const float*)d_in[7];
  const float* sp_ln1_b  = (const float*)d_in[8];
  const float* sp_ff1_w  = (const float*)d_in[9];
  const float* sp_ff1_b  = (const float*)d_in[10];
  const float* sp_ff2_w  = (const float*)d_in[11];
  const float* sp_ff2_b  = (const float*)d_in[12];
  const float* sp_ln2_w  = (const float*)d_in[13];
  const float* sp_ln2_b  = (const float*)d_in[14];
  const float* norm_in_w = (const float*)d_in[15];
  const float* norm_in_b = (const float*)d_in[16];
  const float* m_in_w    = (const float*)d_in[17];
  const float* m_conv_w  = (const float*)d_in[18];
  const float* m_conv_b  = (const float*)d_in[19];
  const float* m_dt_bias = (const float*)d_in[20];
  const float* m_A_log   = (const float*)d_in[21];
  const float* m_D       = (const float*)d_in[22];
  const float* m_gnorm_w = (const float*)d_in[23];
  const float* m_out_w   = (const float*)d_in[24];
  const float* ln_w      = (const float*)d_in[25];
  const float* ln_b      = (const float*)d_in[26];
  const float* pm_qkv_w  = (const float*)d_in[27];
  const float* pm_qkv_b  = (const float*)d_in[28];
  const float* pm_out_w  = (const float*)d_in[29];
  const float* pm_out_b  = (const float*)d_in[30];
  const float* pm_ln_w   = (const float*)d_in[31];
  const float* pm_ln_b   = (const float*)d_in[32];
  const float* pool_w1   = (const float*)d_in[33];
  const float* pool_b1   = (const float*)d_in[34];
  const float* pool_w2   = (const float*)d_in[35];
  const float* pool_b2   = (const float*)d_in[36];
  const float* head_w1   = (const float*)d_in[37];
  const float* head_b1   = (const float*)d_in[38];
  const float* head_w2   = (const float*)d_in[39];
  const float* head_b2   = (const float*)d_in[40];

  float* ws  = (float*)d_ws;
  float* H   = ws + F_H;
  float* out = (float*)d_out;

  #define U(off) ((ushort*)(ws + (off)))

  // ---- phase 0: weight splits ----
  wsplit(sp_conv_w, U(F_WCONVH), U(F_WCONVM), U(F_WCONVL), DM, NCH, KCONV, stream);
  wsplit(sp_qkv_w,  U(F_WQKVH),  U(F_WQKVM),  U(F_WQKVL),  3*DM, DM, DM, stream);
  wsplit(sp_out_w,  U(F_WOUTH),  U(F_WOUTM),  U(F_WOUTL),  DM, DM, DM, stream);
  wsplit(sp_ff1_w,  U(F_WFF1H),  U(F_WFF1M),  U(F_WFF1L),  DIN, DM, DM, stream);
  wsplit(sp_ff2_w,  U(F_WFF2H),  U(F_WFF2M),  U(F_WFF2L),  DM, DIN, DIN, stream);
  for (int i = 0; i < 4; i++) {
    size_t wo = (size_t)i*DPROJ*DM;
    wsplit(m_in_w + wo, U(F_WINH)+wo, U(F_WINM)+wo, U(F_WINL)+wo, DPROJ, DM, DM, stream);
    size_t wo2 = (size_t)i*DM*DIN;
    wsplit(m_out_w + wo2, U(F_WMOH)+wo2, U(F_WMOM)+wo2, U(F_WMOL)+wo2, DM, DIN, DIN, stream);
  }
  wsplit(pm_qkv_w, U(F_WPQH), U(F_WPQM), U(F_WPQL), 3*DM, DM, DM, stream);
  wsplit(pm_out_w, U(F_WPOH), U(F_WPOM), U(F_WPOL), DM, DM, DM, stream);
  wsplit(pool_w1,  U(F_WPLH), U(F_WPLM), U(F_WPLL), 80, DM, DM, stream);

  // ---- phase A: input proj + spatial MHA + FF (per chunk of 32 seqs) ----
  for (int c = 0; c < NCHUNK; c++) {
    float* Hc = H + (size_t)c*RC*DM;
    hipLaunchKernelGGL(k_tsplit, dim3((RC*KCONV+255)/256), dim3(256), 0, stream, x,
                       U(S_XTH), U(S_XTM), U(S_XTL), c*RC);
    mgemm(U(S_XTH), U(S_XTM), U(S_XTL), U(F_WCONVH), U(F_WCONVM), U(F_WCONVL), sp_conv_b,
          Hc, U(S_HH), U(S_HM), U(S_HL), RC, DM, KCONV, 0, 0, stream);
    mgemm(U(S_HH), U(S_HM), U(S_HL), U(F_WQKVH), U(F_WQKVM), U(F_WQKVL), sp_qkv_b,
          ws + S_QKV, nullptr, nullptr, nullptr, RC, 3*DM, DM, 0, 0, stream);
    hipLaunchKernelGGL(k_attn1, dim3(CH*NH), dim3(256), 0, stream, ws + S_QKV,
                       U(S_TH), U(S_TM), U(S_TL), ws + S_ML);
    hipLaunchKernelGGL(k_attnmean, dim3(7,7,CH), dim3(256), 0, stream, ws + S_QKV,
                       ws + S_ML, out + O_A1 + (size_t)c*RC*LL);
    mgemm(U(S_TH), U(S_TM), U(S_TL), U(F_WOUTH), U(F_WOUTM), U(F_WOUTL), sp_out_b,
          ws + S_DEST, nullptr, nullptr, nullptr, RC, DM, DM, 0, 0, stream);
    hipLaunchKernelGGL(k_ln, dim3(RC/4), dim3(256), 0, stream, Hc, ws + S_DEST,
                       Hc, U(S_HH), U(S_HM), U(S_HL), sp_ln1_w, sp_ln1_b, RC);
    mgemm(U(S_HH), U(S_HM), U(S_HL), U(F_WFF1H), U(F_WFF1M), U(F_WFF1L), sp_ff1_b,
          nullptr, U(S_FF1H), U(S_FF1M), U(S_FF1L), RC, DIN, DM, 1, 0, stream);
    mgemm(U(S_FF1H), U(S_FF1M), U(S_FF1L), U(F_WFF2H), U(F_WFF2M), U(F_WFF2L), sp_ff2_b,
          ws + S_DEST, nullptr, nullptr, nullptr, RC, DM, DIN, 0, 0, stream);
    hipLaunchKernelGGL(k_ln2x, dim3(RC/4), dim3(256), 0, stream, Hc, ws + S_DEST,
                       sp_ln2_w, sp_ln2_b, norm_in_w, norm_in_b, Hc, RC);
  }

  // ---- phase B: mamba layers (per layer per chunk of 16 seqs) ----
  for (int i = 0; i < 4; i++) {
    const ushort* WIH = U(F_WINH) + (size_t)i*DPROJ*DM;
    const ushort* WIM = U(F_WINM) + (size_t)i*DPROJ*DM;
    const ushort* WIL = U(F_WINL) + (size_t)i*DPROJ*DM;
    const ushort* WOH = U(F_WMOH) + (size_t)i*DM*DIN;
    const ushort* WOM = U(F_WMOM) + (size_t)i*DM*DIN;
    const ushort* WOL = U(F_WMOL) + (size_t)i*DM*DIN;
    for (int c = 0; c < NCHUNKB; c++) {
      float* Hc = H + (size_t)c*RCB*DM;
      hipLaunchKernelGGL(k_ln, dim3(RCB/4), dim3(256), 0, stream, Hc, (const float*)nullptr,
                         (float*)nullptr, U(S_MTH), U(S_MTM), U(S_MTL),
                         ln_w + (size_t)i*DM, ln_b + (size_t)i*DM, RCB);
      mgemm(U(S_MTH), U(S_MTM), U(S_MTL), WIH, WIM, WIL, nullptr,
            ws + S_BIG, nullptr, nullptr, nullptr, RCB, DPROJ, DM, 0, 0, stream);
      hipLaunchKernelGGL(k_conv, dim3((RCB*CDIM+255)/256), dim3(256), 0, stream, ws + S_BIG,
                         m_conv_w + (size_t)i*CDIM*4, m_conv_b + (size_t)i*CDIM, ws + S_XC, RCB);
      hipLaunchKernelGGL(k_scan, dim3(CHB*HM), dim3(256), 0, stream, ws + S_XC, ws + S_BIG,
                         m_dt_bias + (size_t)i*HM, m_A_log + (size_t)i*HM, ws + S_YC);
      hipLaunchKernelGGL(k_mpost, dim3(RCB/4), dim3(256), 0, stream, ws + S_YC, ws + S_XC, ws + S_BIG,
                         m_D + (size_t)i*HM, m_gnorm_w + (size_t)i*DIN,
                         U(S_YH), U(S_YM), U(S_YL), RCB);
      mgemm(U(S_YH), U(S_YM), U(S_YL), WOH, WOM, WOL, nullptr,
            Hc, nullptr, nullptr, nullptr, RCB, DM, DIN, 0, 1, stream);
    }
  }

  // ---- phase C: post MHA + pooling prep (per chunk of 32 seqs) ----
  for (int c = 0; c < NCHUNK; c++) {
    float* Hc = H + (size_t)c*RC*DM;
    hipLaunchKernelGGL(k_split, dim3((RC*DM+255)/256), dim3(256), 0, stream, Hc,
                       U(S_HH), U(S_HM), U(S_HL), RC*DM);
    mgemm(U(S_HH), U(S_HM), U(S_HL), U(F_WPQH), U(F_WPQM), U(F_WPQL), pm_qkv_b,
          ws + S_QKV, nullptr, nullptr, nullptr, RC, 3*DM, DM, 0, 0, stream);
    hipLaunchKernelGGL(k_attn1, dim3(CH*NH), dim3(256), 0, stream, ws + S_QKV,
                       U(S_TH), U(S_TM), U(S_TL), ws + S_ML);
    hipLaunchKernelGGL(k_attnmean, dim3(7,7,CH), dim3(256), 0, stream, ws + S_QKV,
                       ws + S_ML, out + O_A2 + (size_t)c*RC*LL);
    mgemm(U(S_TH), U(S_TM), U(S_TL), U(F_WPOH), U(F_WPOM), U(F_WPOL), pm_out_b,
          ws + S_DEST, nullptr, nullptr, nullptr, RC, DM, DM, 0, 0, stream);
    hipLaunchKernelGGL(k_ln, dim3(RC/4), dim3(256), 0, stream, Hc, ws + S_DEST,
                       Hc, U(S_HH), U(S_HM), U(S_HL), pm_ln_w, pm_ln_b, RC);
    mgemm(U(S_HH), U(S_HM), U(S_HL), U(F_WPLH), U(F_WPLM), U(F_WPLL), pool_b1,
          ws + S_P1, nullptr, nullptr, nullptr, RC, 80, DM, 2, 0, stream);
    hipLaunchKernelGGL(k_pool2, dim3((RC+255)/256), dim3(256), 0, stream, ws + S_P1, pool_w2, pool_b2,
                       ws + S_LOG + (size_t)c*RC, RC);
  }

  // ---- phase D: pooling + head ----
  hipLaunchKernelGGL(k_pool, dim3(BB), dim3(256), 0, stream, ws + S_LOG, H, out + O_A, ws + S_PL);
  hipLaunchKernelGGL(k_gemm, dim3((160+BN-1)/BN, (BB+BM-1)/BM), dim3(256), 0, stream,
                     ws + S_PL, head_w1, head_b1, ws + S_HR, BB, 160, DM, 1, 0);
  hipLaunchKernelGGL(k_head2, dim3(1), dim3(128), 0, stream, ws + S_HR, head_w2, head_b2, out + O_OUT);
}

// Round 6
// 7300.388 us; speedup vs baseline: 1.3108x; 1.3108x over previous
//
#include <hip/hip_runtime.h>
#include <math.h>

// ---- problem constants ----
#define BB 128
#define LL 200
#define DM 320
#define RTOT (BB*LL)          // 25600
#define NCH 129
#define DIN 640               // 2*DM
#define HM 20                 // mamba heads
#define PP 32                 // headdim
#define NN 32                 // d_state
#define CDIM 704              // DIN + 2*NN
#define DPROJ 1364            // 2*DIN + 2*NN + HM
#define NH 16                 // attn heads
#define HD 20                 // DM/NH
#define ATTN_SCALE 0.22360679774997896f  // 1/sqrt(20)
#define KCONV 160             // 129 zero-padded to multiple of 32

// batch chunking (sequences independent)
#define CH 32
#define NCHUNK 4
#define RC (CH*LL)            // 6400 rows per chunk

typedef unsigned short ushort;
typedef __attribute__((ext_vector_type(8))) short v8s;
typedef __attribute__((ext_vector_type(4))) float v4f;

static __device__ __forceinline__ float sigmoidf_(float x){ return 1.f/(1.f+__expf(-x)); }
static __device__ __forceinline__ float geluf_(float x){ return 0.5f*x*(1.f+erff(x*0.70710678118654752f)); }
static __device__ __forceinline__ ushort f2bf(float f){
  unsigned u = __float_as_uint(f);
  u = (u + 0x7FFFu + ((u>>16)&1u)) >> 16;
  return (ushort)u;
}
static __device__ __forceinline__ float bf2f(ushort h){ return __uint_as_float(((unsigned)h)<<16); }
// exact-ish 3-way split: v == h + m + l to within 2^-26 relative
static __device__ __forceinline__ void split3(float v, ushort* h, ushort* m, ushort* l){
  ushort hh = f2bf(v);
  float r1 = v - bf2f(hh);
  ushort mm = f2bf(r1);
  float r2 = r1 - bf2f(mm);
  *h = hh; *m = mm; *l = f2bf(r2);
}

#define GLL(g, s) __builtin_amdgcn_global_load_lds( \
    (const __attribute__((address_space(1))) unsigned int*)(g), \
    (__attribute__((address_space(3))) unsigned int*)(s), 16, 0, 0)

// ================= bf16x6 MFMA GEMM (fp32-accurate via exact 3-way split) =================
// C[M,N] = act(A[M,K] @ W[N,K]^T + bias) (+C if accum)
// A,W pre-split into bf16 h/m/l. M mult of 128, K mult of 32, N masked.
// lda = row stride of the A split arrays in USHORTS (normally == K).
// grid: (ceil(N/128), M/128), 256 threads (4 waves, 2x2 of 64x64 wave tiles)
__global__ __launch_bounds__(256) void k_mgemm(
    const ushort* __restrict__ AH, const ushort* __restrict__ AM, const ushort* __restrict__ AL,
    const ushort* __restrict__ WH, const ushort* __restrict__ WM, const ushort* __restrict__ WL,
    const float* __restrict__ bias,
    float* __restrict__ outF, ushort* __restrict__ outH, ushort* __restrict__ outM, ushort* __restrict__ outL,
    int M, int N, int K, int lda, int act, int accum){
  __shared__ ushort sA0[128*32];
  __shared__ ushort sA1[128*32];
  __shared__ ushort sA2[128*32];
  __shared__ ushort sW0[128*32];
  __shared__ ushort sW1[128*32];
  __shared__ ushort sW2[128*32];
  int tid = threadIdx.x;
  int wid = tid>>6, lane = tid&63;
  int quad = lane>>4, col = lane&15;
  int m0 = blockIdx.y*128, n0 = blockIdx.x*128;
  int wm = (wid&1)*64, wn = (wid>>1)*64;
  v4f acc[4][4];
  #pragma unroll
  for (int i=0;i<4;i++)
    #pragma unroll
    for (int j=0;j<4;j++) acc[i][j] = (v4f)(0.f);

  // DMA staging: wave wid stages LDS rows [32*wid, 32*wid+32) of each array,
  // two 16-row ops per array. lane l -> row 32*wid+16*s+(l>>2), kcols (l&3)*8.
  // LDS dest = wave-uniform base + lane*16B (matches row-major layout exactly).
  int rl = lane>>2, kc8 = (lane&3)<<3;
  size_t aoff0 = (size_t)(m0 + 32*wid + rl)*lda + kc8;
  size_t aoff1 = aoff0 + (size_t)16*lda;
  int wr0 = n0 + 32*wid + rl;      if (wr0 > N-1) wr0 = N-1;
  int wr1 = n0 + 32*wid + 16 + rl; if (wr1 > N-1) wr1 = N-1;
  size_t woff0 = (size_t)wr0*K + kc8;
  size_t woff1 = (size_t)wr1*K + kc8;
  int sb0 = wid*1024, sb1 = wid*1024 + 512;   // ushort indices

  for (int kb = 0; kb < K; kb += 32) {
    GLL(AH+aoff0+kb, &sA0[sb0]); GLL(AH+aoff1+kb, &sA0[sb1]);
    GLL(AM+aoff0+kb, &sA1[sb0]); GLL(AM+aoff1+kb, &sA1[sb1]);
    GLL(AL+aoff0+kb, &sA2[sb0]); GLL(AL+aoff1+kb, &sA2[sb1]);
    GLL(WH+woff0+kb, &sW0[sb0]); GLL(WH+woff1+kb, &sW0[sb1]);
    GLL(WM+woff0+kb, &sW1[sb0]); GLL(WM+woff1+kb, &sW1[sb1]);
    GLL(WL+woff0+kb, &sW2[sb0]); GLL(WL+woff1+kb, &sW2[sb1]);
    __syncthreads();
    v8s af[3][4];
    #pragma unroll
    for (int i=0;i<4;i++){
      int ro = (wm+16*i+col)*32 + quad*8;
      af[0][i] = *(const v8s*)&sA0[ro];
      af[1][i] = *(const v8s*)&sA1[ro];
      af[2][i] = *(const v8s*)&sA2[ro];
    }
    #pragma unroll
    for (int j=0;j<4;j++){
      int ro = (wn+16*j+col)*32 + quad*8;
      v8s b0 = *(const v8s*)&sW0[ro];
      v8s b1 = *(const v8s*)&sW1[ro];
      v8s b2 = *(const v8s*)&sW2[ro];
      #pragma unroll
      for (int i=0;i<4;i++){
        // smallest-first accumulate; dropped terms <= 2^-26
        acc[i][j] = __builtin_amdgcn_mfma_f32_16x16x32_bf16(af[2][i], b0, acc[i][j], 0,0,0); // al*bh
        acc[i][j] = __builtin_amdgcn_mfma_f32_16x16x32_bf16(af[1][i], b1, acc[i][j], 0,0,0); // am*bm
        acc[i][j] = __builtin_amdgcn_mfma_f32_16x16x32_bf16(af[0][i], b2, acc[i][j], 0,0,0); // ah*bl
        acc[i][j] = __builtin_amdgcn_mfma_f32_16x16x32_bf16(af[1][i], b0, acc[i][j], 0,0,0); // am*bh
        acc[i][j] = __builtin_amdgcn_mfma_f32_16x16x32_bf16(af[0][i], b1, acc[i][j], 0,0,0); // ah*bm
        acc[i][j] = __builtin_amdgcn_mfma_f32_16x16x32_bf16(af[0][i], b0, acc[i][j], 0,0,0); // ah*bh
      }
    }
    __syncthreads();
  }
  // epilogue: C/D layout col=lane&15, row=quad*4+reg
  #pragma unroll
  for (int i=0;i<4;i++){
    int mb = m0 + wm + 16*i + quad*4;
    #pragma unroll
    for (int j=0;j<4;j++){
      int n = n0 + wn + 16*j + col;
      if (n >= N) continue;
      float bv = bias ? bias[n] : 0.f;
      #pragma unroll
      for (int r=0;r<4;r++){
        float v = acc[i][j][r] + bv;
        if (act == 1) v = geluf_(v);
        else if (act == 2) v = tanhf(v);
        size_t off = (size_t)(mb+r)*N + n;
        if (accum) v += outF[off];
        if (outF) outF[off] = v;
        if (outH) split3(v, outH+off, outM+off, outL+off);
      }
    }
  }
}

// ================= fp32 GEMM (tiny: head1 only) =================
#define BM 128
#define BN 64
#define BKK 16
__global__ __launch_bounds__(256) void k_gemm(const float* __restrict__ A, const float* __restrict__ W,
    const float* __restrict__ bias, float* __restrict__ C, int M, int N, int K, int act, int accum){
  __shared__ float As[BKK][BM+4];
  __shared__ float Ws[BKK][BN+4];
  int tid = threadIdx.x;
  int m0 = blockIdx.y*BM, n0 = blockIdx.x*BN;
  int tx = tid & 15, ty = tid >> 4;
  float acc[8][4];
  #pragma unroll
  for (int i=0;i<8;i++)
    #pragma unroll
    for (int j=0;j<4;j++) acc[i][j]=0.f;
  for (int k0 = 0; k0 < K; k0 += BKK) {
    int r = tid >> 2, c4 = (tid & 3) << 2;
    #pragma unroll
    for (int hfl = 0; hfl < 2; hfl++) {
      int rr = r + hfl*64;
      float4 v = make_float4(0.f,0.f,0.f,0.f);
      if (m0 + rr < M && k0 + c4 < K)
        v = *(const float4*)(A + (size_t)(m0+rr)*K + k0 + c4);
      As[c4+0][rr]=v.x; As[c4+1][rr]=v.y; As[c4+2][rr]=v.z; As[c4+3][rr]=v.w;
    }
    {
      int n = tid >> 2;
      float4 v = make_float4(0.f,0.f,0.f,0.f);
      if (n0 + n < N && k0 + c4 < K)
        v = *(const float4*)(W + (size_t)(n0+n)*K + k0 + c4);
      Ws[c4+0][n]=v.x; Ws[c4+1][n]=v.y; Ws[c4+2][n]=v.z; Ws[c4+3][n]=v.w;
    }
    __syncthreads();
    #pragma unroll
    for (int kk = 0; kk < BKK; kk++) {
      float af[8], bf[4];
      float4 a0 = *(const float4*)&As[kk][ty*8];
      float4 a1 = *(const float4*)&As[kk][ty*8+4];
      af[0]=a0.x; af[1]=a0.y; af[2]=a0.z; af[3]=a0.w;
      af[4]=a1.x; af[5]=a1.y; af[6]=a1.z; af[7]=a1.w;
      float4 b0 = *(const float4*)&Ws[kk][tx*4];
      bf[0]=b0.x; bf[1]=b0.y; bf[2]=b0.z; bf[3]=b0.w;
      #pragma unroll
      for (int i=0;i<8;i++)
        #pragma unroll
        for (int j=0;j<4;j++) acc[i][j] = fmaf(af[i], bf[j], acc[i][j]);
    }
    __syncthreads();
  }
  #pragma unroll
  for (int i=0;i<8;i++){
    int m = m0 + ty*8 + i;
    if (m >= M) continue;
    #pragma unroll
    for (int j=0;j<4;j++){
      int n = n0 + tx*4 + j;
      if (n >= N) continue;
      float v = acc[i][j];
      if (bias) v += bias[n];
      if (act == 1) v = geluf_(v);
      else if (act == 2) v = tanhf(v);
      size_t off = (size_t)m*N + n;
      if (accum) v += C[off];
      C[off] = v;
    }
  }
}

// ================= splits =================
__global__ __launch_bounds__(256) void k_wsplit(const float* __restrict__ src, ushort* __restrict__ hi,
    ushort* __restrict__ mi, ushort* __restrict__ lo, int N, int K, int Kp){
  int idx = blockIdx.x*256 + threadIdx.x;
  if (idx >= N*Kp) return;
  int n = idx / Kp, k = idx - n*Kp;
  float v = (k < K) ? src[(size_t)n*K + k] : 0.f;
  split3(v, hi+idx, mi+idx, lo+idx);
}

__global__ __launch_bounds__(256) void k_split(const float* __restrict__ src, ushort* __restrict__ hi,
    ushort* __restrict__ mi, ushort* __restrict__ lo, int n){
  int idx = blockIdx.x*256 + threadIdx.x;
  if (idx >= n) return;
  split3(src[idx], hi+idx, mi+idx, lo+idx);
}

// transpose+pad+split one chunk of rows: rows [r0g, r0g+RC)
__global__ __launch_bounds__(256) void k_tsplit(const float* __restrict__ x, ushort* __restrict__ hi,
    ushort* __restrict__ mi, ushort* __restrict__ lo, int r0g){
  int idx = blockIdx.x*256 + threadIdx.x;
  if (idx >= RC*KCONV) return;
  int r = idx / KCONV, c = idx - r*KCONV;
  int gr = r0g + r;
  int b = gr / LL, l = gr - b*LL;
  float v = (c < NCH) ? x[((size_t)b*NCH + c)*LL + l] : 0.f;
  split3(v, hi+idx, mi+idx, lo+idx);
}

// ================= LayerNorm (D=320), optional add, outputs fp32 and/or bf16 h/m/l
__global__ __launch_bounds__(256) void k_ln(const float* __restrict__ A, const float* __restrict__ Badd,
    float* __restrict__ Of, ushort* __restrict__ Oh, ushort* __restrict__ Om, ushort* __restrict__ Ol,
    const float* __restrict__ w, const float* __restrict__ b, int nrows){
  int wid = threadIdx.x >> 6, lane = threadIdx.x & 63;
  int row = blockIdx.x*4 + wid;
  if (row >= nrows) return;
  const float* a = A + (size_t)row*DM;
  float x[5]; float s = 0.f;
  #pragma unroll
  for (int j=0;j<5;j++){
    int c = lane + j*64;
    x[j] = a[c];
    if (Badd) x[j] += Badd[(size_t)row*DM + c];
    s += x[j];
  }
  #pragma unroll
  for (int m=1;m<64;m<<=1) s += __shfl_xor(s, m);
  float mean = s * (1.f/DM);
  float vs = 0.f;
  #pragma unroll
  for (int j=0;j<5;j++){ float d = x[j]-mean; vs += d*d; }
  #pragma unroll
  for (int m=1;m<64;m<<=1) vs += __shfl_xor(vs, m);
  float inv = rsqrtf(vs*(1.f/DM) + 1e-5f);
  #pragma unroll
  for (int j=0;j<5;j++){
    int c = lane + j*64;
    float v = (x[j]-mean)*inv*w[c] + b[c];
    size_t off = (size_t)row*DM + c;
    if (Of) Of[off] = v;
    if (Oh) split3(v, Oh+off, Om+off, Ol+off);
  }
}

// fused double-LN: O = LN(LN(A+F)*w2+b2)*w3+b3
__global__ __launch_bounds__(256) void k_ln2x(const float* __restrict__ A, const float* __restrict__ F,
    const float* __restrict__ w2, const float* __restrict__ b2,
    const float* __restrict__ w3, const float* __restrict__ b3,
    float* __restrict__ O, int nrows){
  int wid = threadIdx.x >> 6, lane = threadIdx.x & 63;
  int row = blockIdx.x*4 + wid;
  if (row >= nrows) return;
  float x[5]; float s = 0.f;
  #pragma unroll
  for (int j=0;j<5;j++){
    int c = lane + j*64;
    x[j] = A[(size_t)row*DM + c] + F[(size_t)row*DM + c];
    s += x[j];
  }
  #pragma unroll
  for (int m=1;m<64;m<<=1) s += __shfl_xor(s, m);
  float mean = s * (1.f/DM);
  float vs = 0.f;
  #pragma unroll
  for (int j=0;j<5;j++){ float d = x[j]-mean; vs += d*d; }
  #pragma unroll
  for (int m=1;m<64;m<<=1) vs += __shfl_xor(vs, m);
  float inv = rsqrtf(vs*(1.f/DM) + 1e-5f);
  float s2 = 0.f;
  #pragma unroll
  for (int j=0;j<5;j++){
    int c = lane + j*64;
    x[j] = (x[j]-mean)*inv*w2[c] + b2[c];
    s2 += x[j];
  }
  #pragma unroll
  for (int m=1;m<64;m<<=1) s2 += __shfl_xor(s2, m);
  float mean2 = s2 * (1.f/DM);
  float vs2 = 0.f;
  #pragma unroll
  for (int j=0;j<5;j++){ float d = x[j]-mean2; vs2 += d*d; }
  #pragma unroll
  for (int m=1;m<64;m<<=1) vs2 += __shfl_xor(vs2, m);
  float inv2 = rsqrtf(vs2*(1.f/DM) + 1e-5f);
  #pragma unroll
  for (int j=0;j<5;j++){
    int c = lane + j*64;
    O[(size_t)row*DM + c] = (x[j]-mean2)*inv2*w3[c] + b3[c];
  }
}

// ================= attention pass 1: per (b,h), online softmax -> o (h/m/l), store (m,l)
__global__ __launch_bounds__(256) void k_attn1(const float* __restrict__ qkv,
    ushort* __restrict__ oh, ushort* __restrict__ om, ushort* __restrict__ ol, float* __restrict__ ml){
  __shared__ float Ks[LL*HD];
  __shared__ float Vs[LL*HD];
  int b = blockIdx.x >> 4, h = blockIdx.x & 15;
  int tid = threadIdx.x;
  for (int idx = tid; idx < LL*HD; idx += 256) {
    int r = idx / HD, c = idx - r*HD;
    const float* base = qkv + (size_t)(b*LL+r)*960 + h*HD + c;
    Ks[idx] = base[320];
    Vs[idx] = base[640];
  }
  __syncthreads();
  int q = tid;
  if (q >= LL) return;
  const float* qp = qkv + (size_t)(b*LL+q)*960 + h*HD;
  float qr[HD];
  #pragma unroll
  for (int d4 = 0; d4 < 5; d4++) {
    float4 v = *(const float4*)(qp + d4*4);
    qr[d4*4]=v.x; qr[d4*4+1]=v.y; qr[d4*4+2]=v.z; qr[d4*4+3]=v.w;
  }
  float m = -1e30f, l = 0.f;
  float o[HD];
  #pragma unroll
  for (int d=0; d<HD; d++) o[d]=0.f;
  for (int k = 0; k < LL; k++) {
    float s = 0.f;
    #pragma unroll
    for (int d = 0; d < HD; d++) s = fmaf(qr[d], Ks[k*HD+d], s);
    s *= ATTN_SCALE;
    float nm = fmaxf(m, s);
    float al = __expf(m - nm);
    float p  = __expf(s - nm);
    l = l*al + p;
    #pragma unroll
    for (int d = 0; d < HD; d++) o[d] = fmaf(p, Vs[k*HD+d], o[d]*al);
    m = nm;
  }
  float inv = 1.f/l;
  size_t ob = (size_t)(b*LL+q)*DM + h*HD;
  #pragma unroll
  for (int d = 0; d < HD; d++) {
    split3(o[d]*inv, oh+ob+d, om+ob+d, ol+ob+d);
  }
  size_t mlb = ((size_t)(b*NH+h)*LL + q)*2;
  ml[mlb+0] = m;
  ml[mlb+1] = l;
}

// ================= attention pass 2: head-mean probabilities, tiled 32q x 32k
#define QS 164
__global__ __launch_bounds__(256) void k_attnmean(const float* __restrict__ qkv,
    const float* __restrict__ ml, float* __restrict__ outp){
  __shared__ float Qs[32*QS];
  __shared__ float Ksh[32*QS];
  __shared__ float Ms[NH*32];
  __shared__ float Ls[NH*32];
  int b = blockIdx.z;
  int q0 = blockIdx.y*32, k0 = blockIdx.x*32;
  int tid = threadIdx.x;
  for (int idx = tid; idx < NH*32; idx += 256) {
    int h = idx >> 5, r = idx & 31;
    int q = q0 + r;
    float m = 0.f, li = 1.f;
    if (q < LL) {
      size_t base = ((size_t)(b*NH+h)*LL + q)*2;
      m = ml[base+0];
      li = 1.f/ml[base+1];
    }
    Ms[idx] = m; Ls[idx] = li;
  }
  int tx = tid & 31, ty = tid >> 5;
  float acc[4] = {0.f,0.f,0.f,0.f};
  for (int hc = 0; hc < 2; hc++) {
    __syncthreads();
    for (int idx = tid; idx < 32*160; idx += 256) {
      int r = idx / 160, c = idx - r*160;
      int q = q0 + r, k = k0 + r;
      Qs[r*QS + c]  = (q < LL) ? qkv[(size_t)(b*LL+q)*960 + hc*160 + c] : 0.f;
      Ksh[r*QS + c] = (k < LL) ? qkv[(size_t)(b*LL+k)*960 + 320 + hc*160 + c] : 0.f;
    }
    __syncthreads();
    #pragma unroll
    for (int hh = 0; hh < 8; hh++) {
      int h = hc*8 + hh;
      float kf[HD];
      #pragma unroll
      for (int d4 = 0; d4 < 5; d4++) {
        float4 v = *(const float4*)&Ksh[tx*QS + hh*HD + d4*4];
        kf[d4*4]=v.x; kf[d4*4+1]=v.y; kf[d4*4+2]=v.z; kf[d4*4+3]=v.w;
      }
      #pragma unroll
      for (int j = 0; j < 4; j++) {
        int qr = ty + j*8;
        float s = 0.f;
        #pragma unroll
        for (int d4 = 0; d4 < 5; d4++) {
          float4 v = *(const float4*)&Qs[qr*QS + hh*HD + d4*4];
          s += v.x*kf[d4*4] + v.y*kf[d4*4+1] + v.z*kf[d4*4+2] + v.w*kf[d4*4+3];
        }
        acc[j] += __expf(s*ATTN_SCALE - Ms[h*32 + qr]) * Ls[h*32 + qr];
      }
    }
  }
  #pragma unroll
  for (int j = 0; j < 4; j++) {
    int q = q0 + ty + j*8, k = k0 + tx;
    if (q < LL && k < LL)
      outp[(size_t)(b*LL+q)*LL + k] = acc[j] * (1.f/NH);
  }
}

// ================= conv+silu for B/C channels only (xBC channels 640..703)
__global__ __launch_bounds__(256) void k_convBC(const float* __restrict__ big, const float* __restrict__ cw,
    const float* __restrict__ cb, float* __restrict__ xbc, int nrows){
  int idx = blockIdx.x*256 + threadIdx.x;
  if (idx >= nrows*64) return;
  int row = idx >> 6, j = idx & 63;
  int l = row % LL;
  int ch = 640 + j;
  float acc = cb[ch];
  #pragma unroll
  for (int k = 0; k < 4; k++) {
    int li = l - 3 + k;
    if (li >= 0) acc = fmaf(big[(size_t)(row-3+k)*DPROJ + 1280 + j], cw[ch*4+k], acc);
  }
  xbc[idx] = acc * sigmoidf_(acc);
}

// ================= selective scan: fused x-conv + dt/dA + scan + D-skip; b chunk-local
__global__ __launch_bounds__(256) void k_scan(const float* __restrict__ big, const float* __restrict__ xbc,
    const float* __restrict__ cw, const float* __restrict__ cb,
    const float* __restrict__ dtb, const float* __restrict__ alog, const float* __restrict__ Dp,
    float* __restrict__ y){
  __shared__ float xs[LL*PP];
  __shared__ float dts[LL];
  __shared__ float das[LL];
  int b = blockIdx.x / HM, h = blockIdx.x - (blockIdx.x/HM)*HM;
  int tid = threadIdx.x;
  // x-channel conv+silu into LDS (channels h*32..h*32+31 of xBC -> BIG cols 640+...)
  for (int idx = tid; idx < LL*PP; idx += 256) {
    int r = idx >> 5, c = idx & 31;
    int ch = h*PP + c;
    float acc = cb[ch];
    #pragma unroll
    for (int k = 0; k < 4; k++) {
      int li = r - 3 + k;
      if (li >= 0) acc = fmaf(big[(size_t)(b*LL+li)*DPROJ + 640 + ch], cw[ch*4+k], acc);
    }
    xs[idx] = acc * sigmoidf_(acc);
  }
  float aexp = __expf(alog[h]);
  float dtbh = dtb[h];
  for (int idx = tid; idx < LL; idx += 256) {
    float raw = big[(size_t)(b*LL+idx)*DPROJ + 1344 + h] + dtbh;
    float sp = (raw > 30.f) ? raw : log1pf(__expf(raw));
    dts[idx] = sp;
    das[idx] = __expf(-aexp * sp);
  }
  __syncthreads();
  int p = tid >> 3, ng = tid & 7, n0 = ng*4;
  float st0=0.f, st1=0.f, st2=0.f, st3=0.f;
  const float* base = xbc + (size_t)(b*LL)*64;
  float Dh = Dp[h];
  float4 Bc = *(const float4*)(base + n0);
  float4 Cc = *(const float4*)(base + 32 + n0);
  for (int t = 0; t < LL; t++) {
    float4 Bn = Bc, Cn = Cc;
    if (t < LL-1) {
      Bn = *(const float4*)(base + (size_t)(t+1)*64 + n0);
      Cn = *(const float4*)(base + (size_t)(t+1)*64 + 32 + n0);
    }
    float dav = das[t], dtv = dts[t];
    float xv = xs[t*PP + p];
    float coef = dtv * xv;
    st0 = fmaf(coef, Bc.x, st0*dav);
    st1 = fmaf(coef, Bc.y, st1*dav);
    st2 = fmaf(coef, Bc.z, st2*dav);
    st3 = fmaf(coef, Bc.w, st3*dav);
    float part = st0*Cc.x + st1*Cc.y + st2*Cc.z + st3*Cc.w;
    part += __shfl_xor(part, 1);
    part += __shfl_xor(part, 2);
    part += __shfl_xor(part, 4);
    if (ng == 0) y[(size_t)(b*LL+t)*DIN + h*PP + p] = part + Dh*xv;  // D-skip folded in
    Bc = Bn; Cc = Cn;
  }
}

// ================= mamba epilogue: gate + rmsnorm; writes h/m/l IN-PLACE into BIG cols 0..959
__global__ __launch_bounds__(256) void k_mpost(const float* __restrict__ yc, float* __restrict__ big,
    const float* __restrict__ gw, int nrows){
  int wid = threadIdx.x >> 6, lane = threadIdx.x & 63;
  int row = blockIdx.x*4 + wid;
  if (row >= nrows) return;
  float v[10]; float ss = 0.f;
  #pragma unroll
  for (int j = 0; j < 10; j++) {
    int c = lane + j*64;
    float ys = yc[(size_t)row*DIN + c];                 // already includes D-skip
    float z  = big[(size_t)row*DPROJ + c];
    float val = ys * (z * sigmoidf_(z));
    v[j] = val; ss += val*val;
  }
  #pragma unroll
  for (int m=1;m<64;m<<=1) ss += __shfl_xor(ss, m);
  float scale = rsqrtf(ss*(1.f/DIN) + 1e-5f);
  ushort* rowp = (ushort*)(big + (size_t)row*DPROJ);    // z/xBC cols are dead now
  #pragma unroll
  for (int j = 0; j < 10; j++) {
    int c = lane + j*64;
    float val = v[j]*scale*gw[c];
    split3(val, rowp+c, rowp+640+c, rowp+1280+c);
  }
}

// ================= pool2
__global__ __launch_bounds__(256) void k_pool2(const float* __restrict__ A, const float* __restrict__ w2,
    const float* __restrict__ b2, float* __restrict__ out, int nrows){
  int row = blockIdx.x*256 + threadIdx.x;
  if (row >= nrows) return;
  float s = b2[0];
  const float* a = A + (size_t)row*80;
  #pragma unroll
  for (int j = 0; j < 80; j++) s = fmaf(a[j], w2[j], s);
  out[row] = s;
}

// ================= softmax over L + attention-pool
__global__ __launch_bounds__(256) void k_pool(const float* __restrict__ logits, const float* __restrict__ h,
    float* __restrict__ a_out, float* __restrict__ pooled){
  __shared__ float red[256];
  __shared__ float as_[LL];
  int b = blockIdx.x, tid = threadIdx.x;
  float v = (tid < LL) ? logits[b*LL + tid] : -1e30f;
  red[tid] = v; __syncthreads();
  for (int s=128; s>0; s>>=1){ if (tid<s) red[tid]=fmaxf(red[tid],red[tid+s]); __syncthreads(); }
  float mx = red[0]; __syncthreads();
  float e = (tid<LL) ? __expf(v - mx) : 0.f;
  red[tid] = e; __syncthreads();
  for (int s=128; s>0; s>>=1){ if (tid<s) red[tid]+=red[tid+s]; __syncthreads(); }
  float inv = 1.f/red[0];
  if (tid < LL){ float av = e*inv; as_[tid]=av; a_out[b*LL+tid]=av; }
  __syncthreads();
  for (int d = tid; d < DM; d += 256) {
    float s = 0.f;
    for (int l=0;l<LL;l++) s = fmaf(h[(size_t)(b*LL+l)*DM + d], as_[l], s);
    pooled[b*DM + d] = s;
  }
}

// ================= head final dot
__global__ __launch_bounds__(128) void k_head2(const float* __restrict__ hr, const float* __restrict__ w2,
    const float* __restrict__ b2, float* __restrict__ out){
  int b = threadIdx.x;
  if (b >= BB) return;
  float s = b2[0];
  const float* a = hr + (size_t)b*160;
  #pragma unroll
  for (int j = 0; j < 160; j++) s = fmaf(a[j], w2[j], s);
  out[b] = s;
}

// ================= host side =================
static inline void mgemm(const ushort* AH, const ushort* AM, const ushort* AL,
    const ushort* WH, const ushort* WM, const ushort* WL,
    const float* bias, float* outF, ushort* outH, ushort* outM, ushort* outL,
    int M, int N, int K, int lda, int act, int accum, hipStream_t s){
  hipLaunchKernelGGL(k_mgemm, dim3((N+127)/128, M/128), dim3(256), 0, s,
                     AH, AM, AL, WH, WM, WL, bias, outF, outH, outM, outL, M, N, K, lda, act, accum);
}
static inline void wsplit(const float* src, ushort* hi, ushort* mi, ushort* lo, int N, int K, int Kp, hipStream_t s){
  hipLaunchKernelGGL(k_wsplit, dim3((N*Kp+255)/256), dim3(256), 0, s, src, hi, mi, lo, N, K, Kp);
}

// ---- workspace layout (float offsets), total 30,161,920 fl = 120.6 MB (round-5 proven size) ----
#define F_WCONVH ((size_t)8192000)
#define F_WCONVM ((size_t)8217600)
#define F_WCONVL ((size_t)8243200)
#define F_WQKVH  ((size_t)8268800)
#define F_WQKVM  ((size_t)8422400)
#define F_WQKVL  ((size_t)8576000)
#define F_WOUTH  ((size_t)8729600)
#define F_WOUTM  ((size_t)8780800)
#define F_WOUTL  ((size_t)8832000)
#define F_WFF1H  ((size_t)8883200)
#define F_WFF1M  ((size_t)8985600)
#define F_WFF1L  ((size_t)9088000)
#define F_WFF2H  ((size_t)9190400)
#define F_WFF2M  ((size_t)9292800)
#define F_WFF2L  ((size_t)9395200)
#define F_WINH   ((size_t)9497600)
#define F_WINM   ((size_t)10370560)
#define F_WINL   ((size_t)11243520)
#define F_WMOH   ((size_t)12116480)
#define F_WMOM   ((size_t)12526080)
#define F_WMOL   ((size_t)12935680)
#define F_WPQH   ((size_t)13345280)
#define F_WPQM   ((size_t)13498880)
#define F_WPQL   ((size_t)13652480)
#define F_WPOH   ((size_t)13806080)
#define F_WPOM   ((size_t)13857280)
#define F_WPOL   ((size_t)13908480)
#define F_WPLH   ((size_t)13959680)
#define F_WPLM   ((size_t)13972480)
#define F_WPLL   ((size_t)13985280)
#define SB       ((size_t)13998080)
// phase A/C scratch (CH=32, RC=6400) — round-5 proven offsets
#define S_XTH  (SB+0)
#define S_XTM  (SB+512000)
#define S_XTL  (SB+1024000)
#define S_HH   (SB+1536000)
#define S_HM   (SB+2560000)
#define S_HL   (SB+3584000)
#define S_TH   (SB+4608000)
#define S_TM   (SB+5632000)
#define S_TL   (SB+6656000)
#define S_QKV  (SB+7680000)        // 6,144,000 fp32
#define S_FF1H (SB+7680000)        // overlays QKV (dead after attnmean)
#define S_FF1M (SB+9728000)
#define S_FF1L (SB+11776000)
#define S_P1   (SB+7680000)        // phase C overlay of QKV
#define S_ML   (SB+13824000)
#define S_DEST (SB+14028800)       // 2,048,000 -> ends 16,076,800
#define S_LOG  (SB+16076800)
#define S_PL   (SB+16102400)
#define S_HR   (SB+16143360)       // ends 16,163,840
// phase B overlay (CH=32, RC=6400): MT, BIG, XBC(overlays MT), YC
#define B_MTH  (SB+0)              // 1,024,000 each
#define B_MTM  (SB+1024000)
#define B_MTL  (SB+2048000)
#define B_BIG  (SB+3072000)        // 8,729,600 -> ends 11,801,600
#define B_XBC  (SB+0)              // 409,600 (MT dead by then)
#define B_YC   (SB+11801600)       // 4,096,000 -> ends 15,897,600

// output layout (floats): (out, sp_attn, post_attn, a)
#define O_OUT ((size_t)0)
#define O_A1  ((size_t)128)
#define O_A2  ((size_t)5120128)
#define O_A   ((size_t)10240128)

extern "C" void kernel_launch(void* const* d_in, const int* in_sizes, int n_in,
                              void* d_out, int out_size, void* d_ws, size_t ws_size,
                              hipStream_t stream) {
  const float* x         = (const float*)d_in[0];
  const float* sp_conv_w = (const float*)d_in[1];
  const float* sp_conv_b = (const float*)d_in[2];
  const float* sp_qkv_w  = (const float*)d_in[3];
  const float* sp_qkv_b  = (const float*)d_in[4];
  const float* sp_out_w  = (const float*)d_in[5];
  const float* sp_out_b  = (const float*)d_in[6];
  const float* sp_ln1_w  = (const float*)d_in[7];
  const float* sp_ln1_b  = (const float*)d_in[8];
  const float* sp_ff1_w  = (const float*)d_in[9];
  const float* sp_ff1_b  = (const float*)d_in[10];
  const float* sp_ff2_w  = (const float*)d_in[11];
  const float* sp_ff2_b  = (const float*)d_in[12];
  const float* sp_ln2_w  = (const float*)d_in[13];
  const float* sp_ln2_b  = (const float*)d_in[14];
  const float* norm_in_w = (const float*)d_in[15];
  const float* norm_in_b = (const float*)d_in[16];
  const float* m_in_w    = (const float*)d_in[17];
  const float* m_conv_w  = (const float*)d_in[18];
  const float* m_conv_b  = (const float*)d_in[19];
  const float* m_dt_bias = (const float*)d_in[20];
  const float* m_A_log   = (const float*)d_in[21];
  const float* m_D       = (const float*)d_in[22];
  const float* m_gnorm_w = (const float*)d_in[23];
  const float* m_out_w   = (const float*)d_in[24];
  const float* ln_w      = (const float*)d_in[25];
  const float* ln_b      = (const float*)d_in[26];
  const float* pm_qkv_w  = (const float*)d_in[27];
  const float* pm_qkv_b  = (const float*)d_in[28];
  const float* pm_out_w  = (const float*)d_in[29];
  const float* pm_out_b  = (const float*)d_in[30];
  const float* pm_ln_w   = (const float*)d_in[31];
  const float* pm_ln_b   = (const float*)d_in[32];
  const float* pool_w1   = (const float*)d_in[33];
  const float* pool_b1   = (const float*)d_in[34];
  const float* pool_w2   = (const float*)d_in[35];
  const float* pool_b2   = (const float*)d_in[36];
  const float* head_w1   = (const float*)d_in[37];
  const float* head_b1   = (const float*)d_in[38];
  const float* head_w2   = (const float*)d_in[39];
  const float* head_b2   = (const float*)d_in[40];

  float* ws  = (float*)d_ws;
  float* H   = ws;                 // F_H = 0, 8,192,000 fl persistent
  float* out = (float*)d_out;

  #define U(off) ((ushort*)(ws + (off)))

  // ---- phase 0: weight splits ----
  wsplit(sp_conv_w, U(F_WCONVH), U(F_WCONVM), U(F_WCONVL), DM, NCH, KCONV, stream);
  wsplit(sp_qkv_w,  U(F_WQKVH),  U(F_WQKVM),  U(F_WQKVL),  3*DM, DM, DM, stream);
  wsplit(sp_out_w,  U(F_WOUTH),  U(F_WOUTM),  U(F_WOUTL),  DM, DM, DM, stream);
  wsplit(sp_ff1_w,  U(F_WFF1H),  U(F_WFF1M),  U(F_WFF1L),  DIN, DM, DM, stream);
  wsplit(sp_ff2_w,  U(F_WFF2H),  U(F_WFF2M),  U(F_WFF2L),  DM, DIN, DIN, stream);
  for (int i = 0; i < 4; i++) {
    size_t wo = (size_t)i*DPROJ*DM;
    wsplit(m_in_w + wo, U(F_WINH)+wo, U(F_WINM)+wo, U(F_WINL)+wo, DPROJ, DM, DM, stream);
    size_t wo2 = (size_t)i*DM*DIN;
    wsplit(m_out_w + wo2, U(F_WMOH)+wo2, U(F_WMOM)+wo2, U(F_WMOL)+wo2, DM, DIN, DIN, stream);
  }
  wsplit(pm_qkv_w, U(F_WPQH), U(F_WPQM), U(F_WPQL), 3*DM, DM, DM, stream);
  wsplit(pm_out_w, U(F_WPOH), U(F_WPOM), U(F_WPOL), DM, DM, DM, stream);
  wsplit(pool_w1,  U(F_WPLH), U(F_WPLM), U(F_WPLL), 80, DM, DM, stream);

  // ---- phase A: input proj + spatial MHA + FF (per chunk of 32 seqs) ----
  for (int c = 0; c < NCHUNK; c++) {
    float* Hc = H + (size_t)c*RC*DM;
    hipLaunchKernelGGL(k_tsplit, dim3((RC*KCONV+255)/256), dim3(256), 0, stream, x,
                       U(S_XTH), U(S_XTM), U(S_XTL), c*RC);
    mgemm(U(S_XTH), U(S_XTM), U(S_XTL), U(F_WCONVH), U(F_WCONVM), U(F_WCONVL), sp_conv_b,
          Hc, U(S_HH), U(S_HM), U(S_HL), RC, DM, KCONV, KCONV, 0, 0, stream);
    mgemm(U(S_HH), U(S_HM), U(S_HL), U(F_WQKVH), U(F_WQKVM), U(F_WQKVL), sp_qkv_b,
          ws + S_QKV, nullptr, nullptr, nullptr, RC, 3*DM, DM, DM, 0, 0, stream);
    hipLaunchKernelGGL(k_attn1, dim3(CH*NH), dim3(256), 0, stream, ws + S_QKV,
                       U(S_TH), U(S_TM), U(S_TL), ws + S_ML);
    hipLaunchKernelGGL(k_attnmean, dim3(7,7,CH), dim3(256), 0, stream, ws + S_QKV,
                       ws + S_ML, out + O_A1 + (size_t)c*RC*LL);
    mgemm(U(S_TH), U(S_TM), U(S_TL), U(F_WOUTH), U(F_WOUTM), U(F_WOUTL), sp_out_b,
          ws + S_DEST, nullptr, nullptr, nullptr, RC, DM, DM, DM, 0, 0, stream);
    hipLaunchKernelGGL(k_ln, dim3(RC/4), dim3(256), 0, stream, Hc, ws + S_DEST,
                       Hc, U(S_HH), U(S_HM), U(S_HL), sp_ln1_w, sp_ln1_b, RC);
    mgemm(U(S_HH), U(S_HM), U(S_HL), U(F_WFF1H), U(F_WFF1M), U(F_WFF1L), sp_ff1_b,
          nullptr, U(S_FF1H), U(S_FF1M), U(S_FF1L), RC, DIN, DM, DM, 1, 0, stream);
    mgemm(U(S_FF1H), U(S_FF1M), U(S_FF1L), U(F_WFF2H), U(F_WFF2M), U(F_WFF2L), sp_ff2_b,
          ws + S_DEST, nullptr, nullptr, nullptr, RC, DM, DIN, DIN, 0, 0, stream);
    hipLaunchKernelGGL(k_ln2x, dim3(RC/4), dim3(256), 0, stream, Hc, ws + S_DEST,
                       sp_ln2_w, sp_ln2_b, norm_in_w, norm_in_b, Hc, RC);
  }

  // ---- phase B: mamba layers (per layer per chunk of 32 seqs) ----
  for (int i = 0; i < 4; i++) {
    const ushort* WIH = U(F_WINH) + (size_t)i*DPROJ*DM;
    const ushort* WIM = U(F_WINM) + (size_t)i*DPROJ*DM;
    const ushort* WIL = U(F_WINL) + (size_t)i*DPROJ*DM;
    const ushort* WOH = U(F_WMOH) + (size_t)i*DM*DIN;
    const ushort* WOM = U(F_WMOM) + (size_t)i*DM*DIN;
    const ushort* WOL = U(F_WMOL) + (size_t)i*DM*DIN;
    const float* cwi = m_conv_w + (size_t)i*CDIM*4;
    const float* cbi = m_conv_b + (size_t)i*CDIM;
    for (int c = 0; c < NCHUNK; c++) {
      float* Hc = H + (size_t)c*RC*DM;
      float* BIG = ws + B_BIG;
      hipLaunchKernelGGL(k_ln, dim3(RC/4), dim3(256), 0, stream, Hc, (const float*)nullptr,
                         (float*)nullptr, U(B_MTH), U(B_MTM), U(B_MTL),
                         ln_w + (size_t)i*DM, ln_b + (size_t)i*DM, RC);
      mgemm(U(B_MTH), U(B_MTM), U(B_MTL), WIH, WIM, WIL, nullptr,
            BIG, nullptr, nullptr, nullptr, RC, DPROJ, DM, DM, 0, 0, stream);
      hipLaunchKernelGGL(k_convBC, dim3((RC*64+255)/256), dim3(256), 0, stream, BIG,
                         cwi, cbi, ws + B_XBC, RC);
      hipLaunchKernelGGL(k_scan, dim3(CH*HM), dim3(256), 0, stream, BIG, ws + B_XBC,
                         cwi, cbi, m_dt_bias + (size_t)i*HM, m_A_log + (size_t)i*HM,
                         m_D + (size_t)i*HM, ws + B_YC);
      hipLaunchKernelGGL(k_mpost, dim3(RC/4), dim3(256), 0, stream, ws + B_YC, BIG,
                         m_gnorm_w + (size_t)i*DIN, RC);
      // out-proj reads h/m/l embedded in BIG rows (cols 0/640/1280 us), lda = DPROJ*2 ushorts
      mgemm((const ushort*)BIG, (const ushort*)BIG + 640, (const ushort*)BIG + 1280,
            WOH, WOM, WOL, nullptr, Hc, nullptr, nullptr, nullptr,
            RC, DM, DIN, DPROJ*2, 0, 1, stream);
    }
  }

  // ---- phase C: post MHA + pooling prep (per chunk of 32 seqs) ----
  for (int c = 0; c < NCHUNK; c++) {
    float* Hc = H + (size_t)c*RC*DM;
    hipLaunchKernelGGL(k_split, dim3((RC*DM+255)/256), dim3(256), 0, stream, Hc,
                       U(S_HH), U(S_HM), U(S_HL), RC*DM);
    mgemm(U(S_HH), U(S_HM), U(S_HL), U(F_WPQH), U(F_WPQM), U(F_WPQL), pm_qkv_b,
          ws + S_QKV, nullptr, nullptr, nullptr, RC, 3*DM, DM, DM, 0, 0, stream);
    hipLaunchKernelGGL(k_attn1, dim3(CH*NH), dim3(256), 0, stream, ws + S_QKV,
                       U(S_TH), U(S_TM), U(S_TL), ws + S_ML);
    hipLaunchKernelGGL(k_attnmean, dim3(7,7,CH), dim3(256), 0, stream, ws + S_QKV,
                       ws + S_ML, out + O_A2 + (size_t)c*RC*LL);
    mgemm(U(S_TH), U(S_TM), U(S_TL), U(F_WPOH), U(F_WPOM), U(F_WPOL), pm_out_b,
          ws + S_DEST, nullptr, nullptr, nullptr, RC, DM, DM, DM, 0, 0, stream);
    hipLaunchKernelGGL(k_ln, dim3(RC/4), dim3(256), 0, stream, Hc, ws + S_DEST,
                       Hc, U(S_HH), U(S_HM), U(S_HL), pm_ln_w, pm_ln_b, RC);
    mgemm(U(S_HH), U(S_HM), U(S_HL), U(F_WPLH), U(F_WPLM), U(F_WPLL), pool_b1,
          ws + S_P1, nullptr, nullptr, nullptr, RC, 80, DM, DM, 2, 0, stream);
    hipLaunchKernelGGL(k_pool2, dim3((RC+255)/256), dim3(256), 0, stream, ws + S_P1, pool_w2, pool_b2,
                       ws + S_LOG + (size_t)c*RC, RC);
  }

  // ---- phase D: pooling + head ----
  hipLaunchKernelGGL(k_pool, dim3(BB), dim3(256), 0, stream, ws + S_LOG, H, out + O_A, ws + S_PL);
  hipLaunchKernelGGL(k_gemm, dim3((160+BN-1)/BN, (BB+BM-1)/BM), dim3(256), 0, stream,
                     ws + S_PL, head_w1, head_b1, ws + S_HR, BB, 160, DM, 1, 0);
  hipLaunchKernelGGL(k_head2, dim3(1), dim3(128), 0, stream, ws + S_HR, head_w2, head_b2, out + O_OUT);
}

// Round 7
// 7107.779 us; speedup vs baseline: 1.3463x; 1.0271x over previous
//
#include <hip/hip_runtime.h>
#include <math.h>

// ---- problem constants ----
#define BB 128
#define LL 200
#define DM 320
#define RTOT (BB*LL)          // 25600
#define NCH 129
#define DIN 640               // 2*DM
#define HM 20                 // mamba heads
#define PP 32                 // headdim
#define NN 32                 // d_state
#define CDIM 704              // DIN + 2*NN
#define DPROJ 1364            // 2*DIN + 2*NN + HM
#define NH 16                 // attn heads
#define HD 20                 // DM/NH
#define ATTN_SCALE 0.22360679774997896f  // 1/sqrt(20)
#define KCONV 160             // 129 zero-padded to multiple of 32

// batch chunking (sequences independent)
#define CH 32
#define NCHUNK 4
#define RC (CH*LL)            // 6400 rows per chunk

typedef unsigned short ushort;
typedef __attribute__((ext_vector_type(8))) short v8s;
typedef __attribute__((ext_vector_type(4))) float v4f;

static __device__ __forceinline__ float sigmoidf_(float x){ return 1.f/(1.f+__expf(-x)); }
static __device__ __forceinline__ float geluf_(float x){ return 0.5f*x*(1.f+erff(x*0.70710678118654752f)); }
static __device__ __forceinline__ ushort f2bf(float f){
  unsigned u = __float_as_uint(f);
  u = (u + 0x7FFFu + ((u>>16)&1u)) >> 16;
  return (ushort)u;
}
static __device__ __forceinline__ float bf2f(ushort h){ return __uint_as_float(((unsigned)h)<<16); }
// exact-ish 3-way split: v == h + m + l to within 2^-26 relative
static __device__ __forceinline__ void split3(float v, ushort* h, ushort* m, ushort* l){
  ushort hh = f2bf(v);
  float r1 = v - bf2f(hh);
  ushort mm = f2bf(r1);
  float r2 = r1 - bf2f(mm);
  *h = hh; *m = mm; *l = f2bf(r2);
}

// DPP lane-swap adds for sum over 8 consecutive lanes (lanes 8k..8k+7).
// xor1 = quad_perm [1,0,3,2] = 0xB1; xor2 = quad_perm [2,3,0,1] = 0x4E;
// cross-quad within 8 = row_half_mirror = 0x141.
static __device__ __forceinline__ float dpp_add_xor1(float v){
  return v + __int_as_float(__builtin_amdgcn_mov_dpp(__float_as_int(v), 0xB1, 0xF, 0xF, true));
}
static __device__ __forceinline__ float dpp_add_xor2(float v){
  return v + __int_as_float(__builtin_amdgcn_mov_dpp(__float_as_int(v), 0x4E, 0xF, 0xF, true));
}
static __device__ __forceinline__ float dpp_add_hm(float v){
  return v + __int_as_float(__builtin_amdgcn_mov_dpp(__float_as_int(v), 0x141, 0xF, 0xF, true));
}

#define GLL(g, s) __builtin_amdgcn_global_load_lds( \
    (const __attribute__((address_space(1))) unsigned int*)(g), \
    (__attribute__((address_space(3))) unsigned int*)(s), 16, 0, 0)

// ================= bf16x6 MFMA GEMM (fp32-accurate via exact 3-way split) =================
// C[M,N] = act(A[M,K] @ W[N,K]^T + bias) (+C if accum)
// A,W pre-split into bf16 h/m/l. M mult of 128, K mult of 32, N masked.
// lda = row stride of the A split arrays in USHORTS (normally == K).
// grid: (ceil(N/128), M/128), 256 threads (4 waves, 2x2 of 64x64 wave tiles)
__global__ __launch_bounds__(256) void k_mgemm(
    const ushort* __restrict__ AH, const ushort* __restrict__ AM, const ushort* __restrict__ AL,
    const ushort* __restrict__ WH, const ushort* __restrict__ WM, const ushort* __restrict__ WL,
    const float* __restrict__ bias,
    float* __restrict__ outF, ushort* __restrict__ outH, ushort* __restrict__ outM, ushort* __restrict__ outL,
    int M, int N, int K, int lda, int act, int accum){
  __shared__ ushort sA0[128*32];
  __shared__ ushort sA1[128*32];
  __shared__ ushort sA2[128*32];
  __shared__ ushort sW0[128*32];
  __shared__ ushort sW1[128*32];
  __shared__ ushort sW2[128*32];
  int tid = threadIdx.x;
  int wid = tid>>6, lane = tid&63;
  int quad = lane>>4, col = lane&15;
  int m0 = blockIdx.y*128, n0 = blockIdx.x*128;
  int wm = (wid&1)*64, wn = (wid>>1)*64;
  v4f acc[4][4];
  #pragma unroll
  for (int i=0;i<4;i++)
    #pragma unroll
    for (int j=0;j<4;j++) acc[i][j] = (v4f)(0.f);

  // DMA staging: wave wid stages LDS rows [32*wid, 32*wid+32) of each array,
  // two 16-row ops per array. lane l -> row 32*wid+16*s+(l>>2), kcols (l&3)*8.
  int rl = lane>>2, kc8 = (lane&3)<<3;
  size_t aoff0 = (size_t)(m0 + 32*wid + rl)*lda + kc8;
  size_t aoff1 = aoff0 + (size_t)16*lda;
  int wr0 = n0 + 32*wid + rl;      if (wr0 > N-1) wr0 = N-1;
  int wr1 = n0 + 32*wid + 16 + rl; if (wr1 > N-1) wr1 = N-1;
  size_t woff0 = (size_t)wr0*K + kc8;
  size_t woff1 = (size_t)wr1*K + kc8;
  int sb0 = wid*1024, sb1 = wid*1024 + 512;   // ushort indices

  for (int kb = 0; kb < K; kb += 32) {
    GLL(AH+aoff0+kb, &sA0[sb0]); GLL(AH+aoff1+kb, &sA0[sb1]);
    GLL(AM+aoff0+kb, &sA1[sb0]); GLL(AM+aoff1+kb, &sA1[sb1]);
    GLL(AL+aoff0+kb, &sA2[sb0]); GLL(AL+aoff1+kb, &sA2[sb1]);
    GLL(WH+woff0+kb, &sW0[sb0]); GLL(WH+woff1+kb, &sW0[sb1]);
    GLL(WM+woff0+kb, &sW1[sb0]); GLL(WM+woff1+kb, &sW1[sb1]);
    GLL(WL+woff0+kb, &sW2[sb0]); GLL(WL+woff1+kb, &sW2[sb1]);
    __syncthreads();
    v8s af[3][4];
    #pragma unroll
    for (int i=0;i<4;i++){
      int ro = (wm+16*i+col)*32 + quad*8;
      af[0][i] = *(const v8s*)&sA0[ro];
      af[1][i] = *(const v8s*)&sA1[ro];
      af[2][i] = *(const v8s*)&sA2[ro];
    }
    #pragma unroll
    for (int j=0;j<4;j++){
      int ro = (wn+16*j+col)*32 + quad*8;
      v8s b0 = *(const v8s*)&sW0[ro];
      v8s b1 = *(const v8s*)&sW1[ro];
      v8s b2 = *(const v8s*)&sW2[ro];
      #pragma unroll
      for (int i=0;i<4;i++){
        // smallest-first accumulate; dropped terms <= 2^-26
        acc[i][j] = __builtin_amdgcn_mfma_f32_16x16x32_bf16(af[2][i], b0, acc[i][j], 0,0,0); // al*bh
        acc[i][j] = __builtin_amdgcn_mfma_f32_16x16x32_bf16(af[1][i], b1, acc[i][j], 0,0,0); // am*bm
        acc[i][j] = __builtin_amdgcn_mfma_f32_16x16x32_bf16(af[0][i], b2, acc[i][j], 0,0,0); // ah*bl
        acc[i][j] = __builtin_amdgcn_mfma_f32_16x16x32_bf16(af[1][i], b0, acc[i][j], 0,0,0); // am*bh
        acc[i][j] = __builtin_amdgcn_mfma_f32_16x16x32_bf16(af[0][i], b1, acc[i][j], 0,0,0); // ah*bm
        acc[i][j] = __builtin_amdgcn_mfma_f32_16x16x32_bf16(af[0][i], b0, acc[i][j], 0,0,0); // ah*bh
      }
    }
    __syncthreads();
  }
  // epilogue: C/D layout col=lane&15, row=quad*4+reg
  #pragma unroll
  for (int i=0;i<4;i++){
    int mb = m0 + wm + 16*i + quad*4;
    #pragma unroll
    for (int j=0;j<4;j++){
      int n = n0 + wn + 16*j + col;
      if (n >= N) continue;
      float bv = bias ? bias[n] : 0.f;
      #pragma unroll
      for (int r=0;r<4;r++){
        float v = acc[i][j][r] + bv;
        if (act == 1) v = geluf_(v);
        else if (act == 2) v = tanhf(v);
        size_t off = (size_t)(mb+r)*N + n;
        if (accum) v += outF[off];
        if (outF) outF[off] = v;
        if (outH) split3(v, outH+off, outM+off, outL+off);
      }
    }
  }
}

// ================= fp32 GEMM (tiny: head1 only) =================
#define BM 128
#define BN 64
#define BKK 16
__global__ __launch_bounds__(256) void k_gemm(const float* __restrict__ A, const float* __restrict__ W,
    const float* __restrict__ bias, float* __restrict__ C, int M, int N, int K, int act, int accum){
  __shared__ float As[BKK][BM+4];
  __shared__ float Ws[BKK][BN+4];
  int tid = threadIdx.x;
  int m0 = blockIdx.y*BM, n0 = blockIdx.x*BN;
  int tx = tid & 15, ty = tid >> 4;
  float acc[8][4];
  #pragma unroll
  for (int i=0;i<8;i++)
    #pragma unroll
    for (int j=0;j<4;j++) acc[i][j]=0.f;
  for (int k0 = 0; k0 < K; k0 += BKK) {
    int r = tid >> 2, c4 = (tid & 3) << 2;
    #pragma unroll
    for (int hfl = 0; hfl < 2; hfl++) {
      int rr = r + hfl*64;
      float4 v = make_float4(0.f,0.f,0.f,0.f);
      if (m0 + rr < M && k0 + c4 < K)
        v = *(const float4*)(A + (size_t)(m0+rr)*K + k0 + c4);
      As[c4+0][rr]=v.x; As[c4+1][rr]=v.y; As[c4+2][rr]=v.z; As[c4+3][rr]=v.w;
    }
    {
      int n = tid >> 2;
      float4 v = make_float4(0.f,0.f,0.f,0.f);
      if (n0 + n < N && k0 + c4 < K)
        v = *(const float4*)(W + (size_t)(n0+n)*K + k0 + c4);
      Ws[c4+0][n]=v.x; Ws[c4+1][n]=v.y; Ws[c4+2][n]=v.z; Ws[c4+3][n]=v.w;
    }
    __syncthreads();
    #pragma unroll
    for (int kk = 0; kk < BKK; kk++) {
      float af[8], bf[4];
      float4 a0 = *(const float4*)&As[kk][ty*8];
      float4 a1 = *(const float4*)&As[kk][ty*8+4];
      af[0]=a0.x; af[1]=a0.y; af[2]=a0.z; af[3]=a0.w;
      af[4]=a1.x; af[5]=a1.y; af[6]=a1.z; af[7]=a1.w;
      float4 b0 = *(const float4*)&Ws[kk][tx*4];
      bf[0]=b0.x; bf[1]=b0.y; bf[2]=b0.z; bf[3]=b0.w;
      #pragma unroll
      for (int i=0;i<8;i++)
        #pragma unroll
        for (int j=0;j<4;j++) acc[i][j] = fmaf(af[i], bf[j], acc[i][j]);
    }
    __syncthreads();
  }
  #pragma unroll
  for (int i=0;i<8;i++){
    int m = m0 + ty*8 + i;
    if (m >= M) continue;
    #pragma unroll
    for (int j=0;j<4;j++){
      int n = n0 + tx*4 + j;
      if (n >= N) continue;
      float v = acc[i][j];
      if (bias) v += bias[n];
      if (act == 1) v = geluf_(v);
      else if (act == 2) v = tanhf(v);
      size_t off = (size_t)m*N + n;
      if (accum) v += C[off];
      C[off] = v;
    }
  }
}

// ================= splits =================
__global__ __launch_bounds__(256) void k_wsplit(const float* __restrict__ src, ushort* __restrict__ hi,
    ushort* __restrict__ mi, ushort* __restrict__ lo, int N, int K, int Kp){
  int idx = blockIdx.x*256 + threadIdx.x;
  if (idx >= N*Kp) return;
  int n = idx / Kp, k = idx - n*Kp;
  float v = (k < K) ? src[(size_t)n*K + k] : 0.f;
  split3(v, hi+idx, mi+idx, lo+idx);
}

__global__ __launch_bounds__(256) void k_split(const float* __restrict__ src, ushort* __restrict__ hi,
    ushort* __restrict__ mi, ushort* __restrict__ lo, int n){
  int idx = blockIdx.x*256 + threadIdx.x;
  if (idx >= n) return;
  split3(src[idx], hi+idx, mi+idx, lo+idx);
}

// transpose+pad+split one chunk of rows: rows [r0g, r0g+RC)
__global__ __launch_bounds__(256) void k_tsplit(const float* __restrict__ x, ushort* __restrict__ hi,
    ushort* __restrict__ mi, ushort* __restrict__ lo, int r0g){
  int idx = blockIdx.x*256 + threadIdx.x;
  if (idx >= RC*KCONV) return;
  int r = idx / KCONV, c = idx - r*KCONV;
  int gr = r0g + r;
  int b = gr / LL, l = gr - b*LL;
  float v = (c < NCH) ? x[((size_t)b*NCH + c)*LL + l] : 0.f;
  split3(v, hi+idx, mi+idx, lo+idx);
}

// ================= LayerNorm (D=320), optional add, outputs fp32 and/or bf16 h/m/l
__global__ __launch_bounds__(256) void k_ln(const float* __restrict__ A, const float* __restrict__ Badd,
    float* __restrict__ Of, ushort* __restrict__ Oh, ushort* __restrict__ Om, ushort* __restrict__ Ol,
    const float* __restrict__ w, const float* __restrict__ b, int nrows){
  int wid = threadIdx.x >> 6, lane = threadIdx.x & 63;
  int row = blockIdx.x*4 + wid;
  if (row >= nrows) return;
  const float* a = A + (size_t)row*DM;
  float x[5]; float s = 0.f;
  #pragma unroll
  for (int j=0;j<5;j++){
    int c = lane + j*64;
    x[j] = a[c];
    if (Badd) x[j] += Badd[(size_t)row*DM + c];
    s += x[j];
  }
  #pragma unroll
  for (int m=1;m<64;m<<=1) s += __shfl_xor(s, m);
  float mean = s * (1.f/DM);
  float vs = 0.f;
  #pragma unroll
  for (int j=0;j<5;j++){ float d = x[j]-mean; vs += d*d; }
  #pragma unroll
  for (int m=1;m<64;m<<=1) vs += __shfl_xor(vs, m);
  float inv = rsqrtf(vs*(1.f/DM) + 1e-5f);
  #pragma unroll
  for (int j=0;j<5;j++){
    int c = lane + j*64;
    float v = (x[j]-mean)*inv*w[c] + b[c];
    size_t off = (size_t)row*DM + c;
    if (Of) Of[off] = v;
    if (Oh) split3(v, Oh+off, Om+off, Ol+off);
  }
}

// fused double-LN: O = LN(LN(A+F)*w2+b2)*w3+b3
__global__ __launch_bounds__(256) void k_ln2x(const float* __restrict__ A, const float* __restrict__ F,
    const float* __restrict__ w2, const float* __restrict__ b2,
    const float* __restrict__ w3, const float* __restrict__ b3,
    float* __restrict__ O, int nrows){
  int wid = threadIdx.x >> 6, lane = threadIdx.x & 63;
  int row = blockIdx.x*4 + wid;
  if (row >= nrows) return;
  float x[5]; float s = 0.f;
  #pragma unroll
  for (int j=0;j<5;j++){
    int c = lane + j*64;
    x[j] = A[(size_t)row*DM + c] + F[(size_t)row*DM + c];
    s += x[j];
  }
  #pragma unroll
  for (int m=1;m<64;m<<=1) s += __shfl_xor(s, m);
  float mean = s * (1.f/DM);
  float vs = 0.f;
  #pragma unroll
  for (int j=0;j<5;j++){ float d = x[j]-mean; vs += d*d; }
  #pragma unroll
  for (int m=1;m<64;m<<=1) vs += __shfl_xor(vs, m);
  float inv = rsqrtf(vs*(1.f/DM) + 1e-5f);
  float s2 = 0.f;
  #pragma unroll
  for (int j=0;j<5;j++){
    int c = lane + j*64;
    x[j] = (x[j]-mean)*inv*w2[c] + b2[c];
    s2 += x[j];
  }
  #pragma unroll
  for (int m=1;m<64;m<<=1) s2 += __shfl_xor(s2, m);
  float mean2 = s2 * (1.f/DM);
  float vs2 = 0.f;
  #pragma unroll
  for (int j=0;j<5;j++){ float d = x[j]-mean2; vs2 += d*d; }
  #pragma unroll
  for (int m=1;m<64;m<<=1) vs2 += __shfl_xor(vs2, m);
  float inv2 = rsqrtf(vs2*(1.f/DM) + 1e-5f);
  #pragma unroll
  for (int j=0;j<5;j++){
    int c = lane + j*64;
    O[(size_t)row*DM + c] = (x[j]-mean2)*inv2*w3[c] + b3[c];
  }
}

// ================= attention pass 1: per (b,h), online softmax -> o (h/m/l), store (m,l)
__global__ __launch_bounds__(256) void k_attn1(const float* __restrict__ qkv,
    ushort* __restrict__ oh, ushort* __restrict__ om, ushort* __restrict__ ol, float* __restrict__ ml){
  __shared__ float Ks[LL*HD];
  __shared__ float Vs[LL*HD];
  int b = blockIdx.x >> 4, h = blockIdx.x & 15;
  int tid = threadIdx.x;
  for (int idx = tid; idx < LL*HD; idx += 256) {
    int r = idx / HD, c = idx - r*HD;
    const float* base = qkv + (size_t)(b*LL+r)*960 + h*HD + c;
    Ks[idx] = base[320];
    Vs[idx] = base[640];
  }
  __syncthreads();
  int q = tid;
  if (q >= LL) return;
  const float* qp = qkv + (size_t)(b*LL+q)*960 + h*HD;
  float qr[HD];
  #pragma unroll
  for (int d4 = 0; d4 < 5; d4++) {
    float4 v = *(const float4*)(qp + d4*4);
    qr[d4*4]=v.x; qr[d4*4+1]=v.y; qr[d4*4+2]=v.z; qr[d4*4+3]=v.w;
  }
  float m = -1e30f, l = 0.f;
  float o[HD];
  #pragma unroll
  for (int d=0; d<HD; d++) o[d]=0.f;
  for (int k = 0; k < LL; k++) {
    float s = 0.f;
    #pragma unroll
    for (int d = 0; d < HD; d++) s = fmaf(qr[d], Ks[k*HD+d], s);
    s *= ATTN_SCALE;
    float nm = fmaxf(m, s);
    float al = __expf(m - nm);
    float p  = __expf(s - nm);
    l = l*al + p;
    #pragma unroll
    for (int d = 0; d < HD; d++) o[d] = fmaf(p, Vs[k*HD+d], o[d]*al);
    m = nm;
  }
  float inv = 1.f/l;
  size_t ob = (size_t)(b*LL+q)*DM + h*HD;
  #pragma unroll
  for (int d = 0; d < HD; d++) {
    split3(o[d]*inv, oh+ob+d, om+ob+d, ol+ob+d);
  }
  size_t mlb = ((size_t)(b*NH+h)*LL + q)*2;
  ml[mlb+0] = m;
  ml[mlb+1] = l;
}

// ================= attention pass 2: head-mean probabilities, tiled 32q x 32k
#define QS 164
__global__ __launch_bounds__(256) void k_attnmean(const float* __restrict__ qkv,
    const float* __restrict__ ml, float* __restrict__ outp){
  __shared__ float Qs[32*QS];
  __shared__ float Ksh[32*QS];
  __shared__ float Ms[NH*32];
  __shared__ float Ls[NH*32];
  int b = blockIdx.z;
  int q0 = blockIdx.y*32, k0 = blockIdx.x*32;
  int tid = threadIdx.x;
  for (int idx = tid; idx < NH*32; idx += 256) {
    int h = idx >> 5, r = idx & 31;
    int q = q0 + r;
    float m = 0.f, li = 1.f;
    if (q < LL) {
      size_t base = ((size_t)(b*NH+h)*LL + q)*2;
      m = ml[base+0];
      li = 1.f/ml[base+1];
    }
    Ms[idx] = m; Ls[idx] = li;
  }
  int tx = tid & 31, ty = tid >> 5;
  float acc[4] = {0.f,0.f,0.f,0.f};
  for (int hc = 0; hc < 2; hc++) {
    __syncthreads();
    for (int idx = tid; idx < 32*160; idx += 256) {
      int r = idx / 160, c = idx - r*160;
      int q = q0 + r, k = k0 + r;
      Qs[r*QS + c]  = (q < LL) ? qkv[(size_t)(b*LL+q)*960 + hc*160 + c] : 0.f;
      Ksh[r*QS + c] = (k < LL) ? qkv[(size_t)(b*LL+k)*960 + 320 + hc*160 + c] : 0.f;
    }
    __syncthreads();
    #pragma unroll
    for (int hh = 0; hh < 8; hh++) {
      int h = hc*8 + hh;
      float kf[HD];
      #pragma unroll
      for (int d4 = 0; d4 < 5; d4++) {
        float4 v = *(const float4*)&Ksh[tx*QS + hh*HD + d4*4];
        kf[d4*4]=v.x; kf[d4*4+1]=v.y; kf[d4*4+2]=v.z; kf[d4*4+3]=v.w;
      }
      #pragma unroll
      for (int j = 0; j < 4; j++) {
        int qr = ty + j*8;
        float s = 0.f;
        #pragma unroll
        for (int d4 = 0; d4 < 5; d4++) {
          float4 v = *(const float4*)&Qs[qr*QS + hh*HD + d4*4];
          s += v.x*kf[d4*4] + v.y*kf[d4*4+1] + v.z*kf[d4*4+2] + v.w*kf[d4*4+3];
        }
        acc[j] += __expf(s*ATTN_SCALE - Ms[h*32 + qr]) * Ls[h*32 + qr];
      }
    }
  }
  #pragma unroll
  for (int j = 0; j < 4; j++) {
    int q = q0 + ty + j*8, k = k0 + tx;
    if (q < LL && k < LL)
      outp[(size_t)(b*LL+q)*LL + k] = acc[j] * (1.f/NH);
  }
}

// ================= conv+silu for B/C channels only (xBC channels 640..703)
__global__ __launch_bounds__(256) void k_convBC(const float* __restrict__ big, const float* __restrict__ cw,
    const float* __restrict__ cb, float* __restrict__ xbc, int nrows){
  int idx = blockIdx.x*256 + threadIdx.x;
  if (idx >= nrows*64) return;
  int row = idx >> 6, j = idx & 63;
  int l = row % LL;
  int ch = 640 + j;
  float acc = cb[ch];
  #pragma unroll
  for (int k = 0; k < 4; k++) {
    int li = l - 3 + k;
    if (li >= 0) acc = fmaf(big[(size_t)(row-3+k)*DPROJ + 1280 + j], cw[ch*4+k], acc);
  }
  xbc[idx] = acc * sigmoidf_(acc);
}

// ================= selective scan v3: fused x-conv + dt/dA + scan + D-skip; b chunk-local
// DPP 8-lane reduce + one-ahead register prefetch of all LDS operands.
__global__ __launch_bounds__(256) void k_scan(const float* __restrict__ big, const float* __restrict__ xbc,
    const float* __restrict__ cw, const float* __restrict__ cb,
    const float* __restrict__ dtb, const float* __restrict__ alog, const float* __restrict__ Dp,
    float* __restrict__ y){
  __shared__ float xs[LL*PP];
  __shared__ float2 dd[LL];   // (dA_t, dt_t)
  int b = blockIdx.x / HM, h = blockIdx.x - (blockIdx.x/HM)*HM;
  int tid = threadIdx.x;
  // x-channel conv+silu into LDS (channels h*32..h*32+31 of xBC -> BIG cols 640+...)
  for (int idx = tid; idx < LL*PP; idx += 256) {
    int r = idx >> 5, c = idx & 31;
    int ch = h*PP + c;
    float acc = cb[ch];
    #pragma unroll
    for (int k = 0; k < 4; k++) {
      int li = r - 3 + k;
      if (li >= 0) acc = fmaf(big[(size_t)(b*LL+li)*DPROJ + 640 + ch], cw[ch*4+k], acc);
    }
    xs[idx] = acc * sigmoidf_(acc);
  }
  float aexp = __expf(alog[h]);
  float dtbh = dtb[h];
  for (int idx = tid; idx < LL; idx += 256) {
    float raw = big[(size_t)(b*LL+idx)*DPROJ + 1344 + h] + dtbh;
    float sp = (raw > 30.f) ? raw : log1pf(__expf(raw));
    dd[idx] = make_float2(__expf(-aexp * sp), sp);
  }
  __syncthreads();
  int p = tid >> 3, ng = tid & 7, n0 = ng*4;
  float st0=0.f, st1=0.f, st2=0.f, st3=0.f;
  const float* base = xbc + (size_t)(b*LL)*64;
  float Dh = Dp[h];
  float4 Bc = *(const float4*)(base + n0);
  float4 Cc = *(const float4*)(base + 32 + n0);
  float  xv = xs[p];
  float2 ddc = dd[0];
  for (int t = 0; t < LL; t++) {
    float4 Bn = Bc, Cn = Cc;
    float  xn = xv;
    float2 ddn = ddc;
    if (t < LL-1) {
      Bn  = *(const float4*)(base + (size_t)(t+1)*64 + n0);
      Cn  = *(const float4*)(base + (size_t)(t+1)*64 + 32 + n0);
      xn  = xs[(t+1)*PP + p];
      ddn = dd[t+1];
    }
    float dav = ddc.x, dtv = ddc.y;
    float coef = dtv * xv;
    st0 = fmaf(coef, Bc.x, st0*dav);
    st1 = fmaf(coef, Bc.y, st1*dav);
    st2 = fmaf(coef, Bc.z, st2*dav);
    st3 = fmaf(coef, Bc.w, st3*dav);
    float part = st0*Cc.x + st1*Cc.y + st2*Cc.z + st3*Cc.w;
    part = dpp_add_xor1(part);    // sum lanes xor 1
    part = dpp_add_xor2(part);    // sum lanes xor 2
    part = dpp_add_hm(part);      // cross-quad within 8-lane group
    if (ng == 0) y[(size_t)(b*LL+t)*DIN + h*PP + p] = part + Dh*xv;  // D-skip folded in
    Bc = Bn; Cc = Cn; xv = xn; ddc = ddn;
  }
}

// ================= mamba epilogue: gate + rmsnorm; writes h/m/l IN-PLACE into BIG cols 0..959
__global__ __launch_bounds__(256) void k_mpost(const float* __restrict__ yc, float* __restrict__ big,
    const float* __restrict__ gw, int nrows){
  int wid = threadIdx.x >> 6, lane = threadIdx.x & 63;
  int row = blockIdx.x*4 + wid;
  if (row >= nrows) return;
  float v[10]; float ss = 0.f;
  #pragma unroll
  for (int j = 0; j < 10; j++) {
    int c = lane + j*64;
    float ys = yc[(size_t)row*DIN + c];                 // already includes D-skip
    float z  = big[(size_t)row*DPROJ + c];
    float val = ys * (z * sigmoidf_(z));
    v[j] = val; ss += val*val;
  }
  #pragma unroll
  for (int m=1;m<64;m<<=1) ss += __shfl_xor(ss, m);
  float scale = rsqrtf(ss*(1.f/DIN) + 1e-5f);
  ushort* rowp = (ushort*)(big + (size_t)row*DPROJ);    // z/xBC cols are dead now
  #pragma unroll
  for (int j = 0; j < 10; j++) {
    int c = lane + j*64;
    float val = v[j]*scale*gw[c];
    split3(val, rowp+c, rowp+640+c, rowp+1280+c);
  }
}

// ================= pool2
__global__ __launch_bounds__(256) void k_pool2(const float* __restrict__ A, const float* __restrict__ w2,
    const float* __restrict__ b2, float* __restrict__ out, int nrows){
  int row = blockIdx.x*256 + threadIdx.x;
  if (row >= nrows) return;
  float s = b2[0];
  const float* a = A + (size_t)row*80;
  #pragma unroll
  for (int j = 0; j < 80; j++) s = fmaf(a[j], w2[j], s);
  out[row] = s;
}

// ================= softmax over L + attention-pool
__global__ __launch_bounds__(256) void k_pool(const float* __restrict__ logits, const float* __restrict__ h,
    float* __restrict__ a_out, float* __restrict__ pooled){
  __shared__ float red[256];
  __shared__ float as_[LL];
  int b = blockIdx.x, tid = threadIdx.x;
  float v = (tid < LL) ? logits[b*LL + tid] : -1e30f;
  red[tid] = v; __syncthreads();
  for (int s=128; s>0; s>>=1){ if (tid<s) red[tid]=fmaxf(red[tid],red[tid+s]); __syncthreads(); }
  float mx = red[0]; __syncthreads();
  float e = (tid<LL) ? __expf(v - mx) : 0.f;
  red[tid] = e; __syncthreads();
  for (int s=128; s>0; s>>=1){ if (tid<s) red[tid]+=red[tid+s]; __syncthreads(); }
  float inv = 1.f/red[0];
  if (tid < LL){ float av = e*inv; as_[tid]=av; a_out[b*LL+tid]=av; }
  __syncthreads();
  for (int d = tid; d < DM; d += 256) {
    float s = 0.f;
    for (int l=0;l<LL;l++) s = fmaf(h[(size_t)(b*LL+l)*DM + d], as_[l], s);
    pooled[b*DM + d] = s;
  }
}

// ================= head final dot
__global__ __launch_bounds__(128) void k_head2(const float* __restrict__ hr, const float* __restrict__ w2,
    const float* __restrict__ b2, float* __restrict__ out){
  int b = threadIdx.x;
  if (b >= BB) return;
  float s = b2[0];
  const float* a = hr + (size_t)b*160;
  #pragma unroll
  for (int j = 0; j < 160; j++) s = fmaf(a[j], w2[j], s);
  out[b] = s;
}

// ================= host side =================
static inline void mgemm(const ushort* AH, const ushort* AM, const ushort* AL,
    const ushort* WH, const ushort* WM, const ushort* WL,
    const float* bias, float* outF, ushort* outH, ushort* outM, ushort* outL,
    int M, int N, int K, int lda, int act, int accum, hipStream_t s){
  hipLaunchKernelGGL(k_mgemm, dim3((N+127)/128, M/128), dim3(256), 0, s,
                     AH, AM, AL, WH, WM, WL, bias, outF, outH, outM, outL, M, N, K, lda, act, accum);
}
static inline void wsplit(const float* src, ushort* hi, ushort* mi, ushort* lo, int N, int K, int Kp, hipStream_t s){
  hipLaunchKernelGGL(k_wsplit, dim3((N*Kp+255)/256), dim3(256), 0, s, src, hi, mi, lo, N, K, Kp);
}

// ---- workspace layout (float offsets), total 30,161,920 fl = 120.6 MB ----
#define F_WCONVH ((size_t)8192000)
#define F_WCONVM ((size_t)8217600)
#define F_WCONVL ((size_t)8243200)
#define F_WQKVH  ((size_t)8268800)
#define F_WQKVM  ((size_t)8422400)
#define F_WQKVL  ((size_t)8576000)
#define F_WOUTH  ((size_t)8729600)
#define F_WOUTM  ((size_t)8780800)
#define F_WOUTL  ((size_t)8832000)
#define F_WFF1H  ((size_t)8883200)
#define F_WFF1M  ((size_t)8985600)
#define F_WFF1L  ((size_t)9088000)
#define F_WFF2H  ((size_t)9190400)
#define F_WFF2M  ((size_t)9292800)
#define F_WFF2L  ((size_t)9395200)
#define F_WINH   ((size_t)9497600)
#define F_WINM   ((size_t)10370560)
#define F_WINL   ((size_t)11243520)
#define F_WMOH   ((size_t)12116480)
#define F_WMOM   ((size_t)12526080)
#define F_WMOL   ((size_t)12935680)
#define F_WPQH   ((size_t)13345280)
#define F_WPQM   ((size_t)13498880)
#define F_WPQL   ((size_t)13652480)
#define F_WPOH   ((size_t)13806080)
#define F_WPOM   ((size_t)13857280)
#define F_WPOL   ((size_t)13908480)
#define F_WPLH   ((size_t)13959680)
#define F_WPLM   ((size_t)13972480)
#define F_WPLL   ((size_t)13985280)
#define SB       ((size_t)13998080)
// phase A/C scratch (CH=32, RC=6400)
#define S_XTH  (SB+0)
#define S_XTM  (SB+512000)
#define S_XTL  (SB+1024000)
#define S_HH   (SB+1536000)
#define S_HM   (SB+2560000)
#define S_HL   (SB+3584000)
#define S_TH   (SB+4608000)
#define S_TM   (SB+5632000)
#define S_TL   (SB+6656000)
#define S_QKV  (SB+7680000)        // 6,144,000 fp32
#define S_FF1H (SB+7680000)        // overlays QKV (dead after attnmean)
#define S_FF1M (SB+9728000)
#define S_FF1L (SB+11776000)
#define S_P1   (SB+7680000)        // phase C overlay of QKV
#define S_ML   (SB+13824000)
#define S_DEST (SB+14028800)       // 2,048,000 -> ends 16,076,800
#define S_LOG  (SB+16076800)
#define S_PL   (SB+16102400)
#define S_HR   (SB+16143360)       // ends 16,163,840
// phase B overlay (CH=32, RC=6400): MT, BIG, XBC(overlays MT), YC
#define B_MTH  (SB+0)              // 1,024,000 each
#define B_MTM  (SB+1024000)
#define B_MTL  (SB+2048000)
#define B_BIG  (SB+3072000)        // 8,729,600 -> ends 11,801,600
#define B_XBC  (SB+0)              // 409,600 (MT dead by then)
#define B_YC   (SB+11801600)       // 4,096,000 -> ends 15,897,600

// output layout (floats): (out, sp_attn, post_attn, a)
#define O_OUT ((size_t)0)
#define O_A1  ((size_t)128)
#define O_A2  ((size_t)5120128)
#define O_A   ((size_t)10240128)

extern "C" void kernel_launch(void* const* d_in, const int* in_sizes, int n_in,
                              void* d_out, int out_size, void* d_ws, size_t ws_size,
                              hipStream_t stream) {
  const float* x         = (const float*)d_in[0];
  const float* sp_conv_w = (const float*)d_in[1];
  const float* sp_conv_b = (const float*)d_in[2];
  const float* sp_qkv_w  = (const float*)d_in[3];
  const float* sp_qkv_b  = (const float*)d_in[4];
  const float* sp_out_w  = (const float*)d_in[5];
  const float* sp_out_b  = (const float*)d_in[6];
  const float* sp_ln1_w  = (const float*)d_in[7];
  const float* sp_ln1_b  = (const float*)d_in[8];
  const float* sp_ff1_w  = (const float*)d_in[9];
  const float* sp_ff1_b  = (const float*)d_in[10];
  const float* sp_ff2_w  = (const float*)d_in[11];
  const float* sp_ff2_b  = (const float*)d_in[12];
  const float* sp_ln2_w  = (const float*)d_in[13];
  const float* sp_ln2_b  = (const float*)d_in[14];
  const float* norm_in_w = (const float*)d_in[15];
  const float* norm_in_b = (const float*)d_in[16];
  const float* m_in_w    = (const float*)d_in[17];
  const float* m_conv_w  = (const float*)d_in[18];
  const float* m_conv_b  = (const float*)d_in[19];
  const float* m_dt_bias = (const float*)d_in[20];
  const float* m_A_log   = (const float*)d_in[21];
  const float* m_D       = (const float*)d_in[22];
  const float* m_gnorm_w = (const float*)d_in[23];
  const float* m_out_w   = (const float*)d_in[24];
  const float* ln_w      = (const float*)d_in[25];
  const float* ln_b      = (const float*)d_in[26];
  const float* pm_qkv_w  = (const float*)d_in[27];
  const float* pm_qkv_b  = (const float*)d_in[28];
  const float* pm_out_w  = (const float*)d_in[29];
  const float* pm_out_b  = (const float*)d_in[30];
  const float* pm_ln_w   = (const float*)d_in[31];
  const float* pm_ln_b   = (const float*)d_in[32];
  const float* pool_w1   = (const float*)d_in[33];
  const float* pool_b1   = (const float*)d_in[34];
  const float* pool_w2   = (const float*)d_in[35];
  const float* pool_b2   = (const float*)d_in[36];
  const float* head_w1   = (const float*)d_in[37];
  const float* head_b1   = (const float*)d_in[38];
  const float* head_w2   = (const float*)d_in[39];
  const float* head_b2   = (const float*)d_in[40];

  float* ws  = (float*)d_ws;
  float* H   = ws;                 // F_H = 0, 8,192,000 fl persistent
  float* out = (float*)d_out;

  #define U(off) ((ushort*)(ws + (off)))

  // ---- phase 0: weight splits ----
  wsplit(sp_conv_w, U(F_WCONVH), U(F_WCONVM), U(F_WCONVL), DM, NCH, KCONV, stream);
  wsplit(sp_qkv_w,  U(F_WQKVH),  U(F_WQKVM),  U(F_WQKVL),  3*DM, DM, DM, stream);
  wsplit(sp_out_w,  U(F_WOUTH),  U(F_WOUTM),  U(F_WOUTL),  DM, DM, DM, stream);
  wsplit(sp_ff1_w,  U(F_WFF1H),  U(F_WFF1M),  U(F_WFF1L),  DIN, DM, DM, stream);
  wsplit(sp_ff2_w,  U(F_WFF2H),  U(F_WFF2M),  U(F_WFF2L),  DM, DIN, DIN, stream);
  for (int i = 0; i < 4; i++) {
    size_t wo = (size_t)i*DPROJ*DM;
    wsplit(m_in_w + wo, U(F_WINH)+wo, U(F_WINM)+wo, U(F_WINL)+wo, DPROJ, DM, DM, stream);
    size_t wo2 = (size_t)i*DM*DIN;
    wsplit(m_out_w + wo2, U(F_WMOH)+wo2, U(F_WMOM)+wo2, U(F_WMOL)+wo2, DM, DIN, DIN, stream);
  }
  wsplit(pm_qkv_w, U(F_WPQH), U(F_WPQM), U(F_WPQL), 3*DM, DM, DM, stream);
  wsplit(pm_out_w, U(F_WPOH), U(F_WPOM), U(F_WPOL), DM, DM, DM, stream);
  wsplit(pool_w1,  U(F_WPLH), U(F_WPLM), U(F_WPLL), 80, DM, DM, stream);

  // ---- phase A: input proj + spatial MHA + FF (per chunk of 32 seqs) ----
  for (int c = 0; c < NCHUNK; c++) {
    float* Hc = H + (size_t)c*RC*DM;
    hipLaunchKernelGGL(k_tsplit, dim3((RC*KCONV+255)/256), dim3(256), 0, stream, x,
                       U(S_XTH), U(S_XTM), U(S_XTL), c*RC);
    mgemm(U(S_XTH), U(S_XTM), U(S_XTL), U(F_WCONVH), U(F_WCONVM), U(F_WCONVL), sp_conv_b,
          Hc, U(S_HH), U(S_HM), U(S_HL), RC, DM, KCONV, KCONV, 0, 0, stream);
    mgemm(U(S_HH), U(S_HM), U(S_HL), U(F_WQKVH), U(F_WQKVM), U(F_WQKVL), sp_qkv_b,
          ws + S_QKV, nullptr, nullptr, nullptr, RC, 3*DM, DM, DM, 0, 0, stream);
    hipLaunchKernelGGL(k_attn1, dim3(CH*NH), dim3(256), 0, stream, ws + S_QKV,
                       U(S_TH), U(S_TM), U(S_TL), ws + S_ML);
    hipLaunchKernelGGL(k_attnmean, dim3(7,7,CH), dim3(256), 0, stream, ws + S_QKV,
                       ws + S_ML, out + O_A1 + (size_t)c*RC*LL);
    mgemm(U(S_TH), U(S_TM), U(S_TL), U(F_WOUTH), U(F_WOUTM), U(F_WOUTL), sp_out_b,
          ws + S_DEST, nullptr, nullptr, nullptr, RC, DM, DM, DM, 0, 0, stream);
    hipLaunchKernelGGL(k_ln, dim3(RC/4), dim3(256), 0, stream, Hc, ws + S_DEST,
                       Hc, U(S_HH), U(S_HM), U(S_HL), sp_ln1_w, sp_ln1_b, RC);
    mgemm(U(S_HH), U(S_HM), U(S_HL), U(F_WFF1H), U(F_WFF1M), U(F_WFF1L), sp_ff1_b,
          nullptr, U(S_FF1H), U(S_FF1M), U(S_FF1L), RC, DIN, DM, DM, 1, 0, stream);
    mgemm(U(S_FF1H), U(S_FF1M), U(S_FF1L), U(F_WFF2H), U(F_WFF2M), U(F_WFF2L), sp_ff2_b,
          ws + S_DEST, nullptr, nullptr, nullptr, RC, DM, DIN, DIN, 0, 0, stream);
    hipLaunchKernelGGL(k_ln2x, dim3(RC/4), dim3(256), 0, stream, Hc, ws + S_DEST,
                       sp_ln2_w, sp_ln2_b, norm_in_w, norm_in_b, Hc, RC);
  }

  // ---- phase B: mamba layers (per layer per chunk of 32 seqs) ----
  for (int i = 0; i < 4; i++) {
    const ushort* WIH = U(F_WINH) + (size_t)i*DPROJ*DM;
    const ushort* WIM = U(F_WINM) + (size_t)i*DPROJ*DM;
    const ushort* WIL = U(F_WINL) + (size_t)i*DPROJ*DM;
    const ushort* WOH = U(F_WMOH) + (size_t)i*DM*DIN;
    const ushort* WOM = U(F_WMOM) + (size_t)i*DM*DIN;
    const ushort* WOL = U(F_WMOL) + (size_t)i*DM*DIN;
    const float* cwi = m_conv_w + (size_t)i*CDIM*4;
    const float* cbi = m_conv_b + (size_t)i*CDIM;
    for (int c = 0; c < NCHUNK; c++) {
      float* Hc = H + (size_t)c*RC*DM;
      float* BIG = ws + B_BIG;
      hipLaunchKernelGGL(k_ln, dim3(RC/4), dim3(256), 0, stream, Hc, (const float*)nullptr,
                         (float*)nullptr, U(B_MTH), U(B_MTM), U(B_MTL),
                         ln_w + (size_t)i*DM, ln_b + (size_t)i*DM, RC);
      mgemm(U(B_MTH), U(B_MTM), U(B_MTL), WIH, WIM, WIL, nullptr,
            BIG, nullptr, nullptr, nullptr, RC, DPROJ, DM, DM, 0, 0, stream);
      hipLaunchKernelGGL(k_convBC, dim3((RC*64+255)/256), dim3(256), 0, stream, BIG,
                         cwi, cbi, ws + B_XBC, RC);
      hipLaunchKernelGGL(k_scan, dim3(CH*HM), dim3(256), 0, stream, BIG, ws + B_XBC,
                         cwi, cbi, m_dt_bias + (size_t)i*HM, m_A_log + (size_t)i*HM,
                         m_D + (size_t)i*HM, ws + B_YC);
      hipLaunchKernelGGL(k_mpost, dim3(RC/4), dim3(256), 0, stream, ws + B_YC, BIG,
                         m_gnorm_w + (size_t)i*DIN, RC);
      // out-proj reads h/m/l embedded in BIG rows (cols 0/640/1280 us), lda = DPROJ*2 ushorts
      mgemm((const ushort*)BIG, (const ushort*)BIG + 640, (const ushort*)BIG + 1280,
            WOH, WOM, WOL, nullptr, Hc, nullptr, nullptr, nullptr,
            RC, DM, DIN, DPROJ*2, 0, 1, stream);
    }
  }

  // ---- phase C: post MHA + pooling prep (per chunk of 32 seqs) ----
  for (int c = 0; c < NCHUNK; c++) {
    float* Hc = H + (size_t)c*RC*DM;
    hipLaunchKernelGGL(k_split, dim3((RC*DM+255)/256), dim3(256), 0, stream, Hc,
                       U(S_HH), U(S_HM), U(S_HL), RC*DM);
    mgemm(U(S_HH), U(S_HM), U(S_HL), U(F_WPQH), U(F_WPQM), U(F_WPQL), pm_qkv_b,
          ws + S_QKV, nullptr, nullptr, nullptr, RC, 3*DM, DM, DM, 0, 0, stream);
    hipLaunchKernelGGL(k_attn1, dim3(CH*NH), dim3(256), 0, stream, ws + S_QKV,
                       U(S_TH), U(S_TM), U(S_TL), ws + S_ML);
    hipLaunchKernelGGL(k_attnmean, dim3(7,7,CH), dim3(256), 0, stream, ws + S_QKV,
                       ws + S_ML, out + O_A2 + (size_t)c*RC*LL);
    mgemm(U(S_TH), U(S_TM), U(S_TL), U(F_WPOH), U(F_WPOM), U(F_WPOL), pm_out_b,
          ws + S_DEST, nullptr, nullptr, nullptr, RC, DM, DM, DM, 0, 0, stream);
    hipLaunchKernelGGL(k_ln, dim3(RC/4), dim3(256), 0, stream, Hc, ws + S_DEST,
                       Hc, U(S_HH), U(S_HM), U(S_HL), pm_ln_w, pm_ln_b, RC);
    mgemm(U(S_HH), U(S_HM), U(S_HL), U(F_WPLH), U(F_WPLM), U(F_WPLL), pool_b1,
          ws + S_P1, nullptr, nullptr, nullptr, RC, 80, DM, DM, 2, 0, stream);
    hipLaunchKernelGGL(k_pool2, dim3((RC+255)/256), dim3(256), 0, stream, ws + S_P1, pool_w2, pool_b2,
                       ws + S_LOG + (size_t)c*RC, RC);
  }

  // ---- phase D: pooling + head ----
  hipLaunchKernelGGL(k_pool, dim3(BB), dim3(256), 0, stream, ws + S_LOG, H, out + O_A, ws + S_PL);
  hipLaunchKernelGGL(k_gemm, dim3((160+BN-1)/BN, (BB+BM-1)/BM), dim3(256), 0, stream,
                     ws + S_PL, head_w1, head_b1, ws + S_HR, BB, 160, DM, 1, 0);
  hipLaunchKernelGGL(k_head2, dim3(1), dim3(128), 0, stream, ws + S_HR, head_w2, head_b2, out + O_OUT);
}

// Round 8
// 6473.935 us; speedup vs baseline: 1.4781x; 1.0979x over previous
//
#include <hip/hip_runtime.h>
#include <math.h>

// ---- problem constants ----
#define BB 128
#define LL 200
#define DM 320
#define RTOT (BB*LL)          // 25600
#define NCH 129
#define DIN 640               // 2*DM
#define HM 20                 // mamba heads
#define PP 32                 // headdim
#define NN 32                 // d_state
#define CDIM 704              // DIN + 2*NN
#define DPROJ 1364            // 2*DIN + 2*NN + HM
#define NH 16                 // attn heads
#define HD 20                 // DM/NH
#define ATTN_SCALE 0.22360679774997896f  // 1/sqrt(20)
#define KCONV 160             // 129 zero-padded to multiple of 32

// batch chunking (sequences independent)
#define CH 32
#define NCHUNK 4
#define RC (CH*LL)            // 6400 rows per chunk

typedef unsigned short ushort;
typedef __attribute__((ext_vector_type(8))) short v8s;
typedef __attribute__((ext_vector_type(4))) float v4f;

static __device__ __forceinline__ float sigmoidf_(float x){ return 1.f/(1.f+__expf(-x)); }
static __device__ __forceinline__ float geluf_(float x){ return 0.5f*x*(1.f+erff(x*0.70710678118654752f)); }
static __device__ __forceinline__ ushort f2bf(float f){
  unsigned u = __float_as_uint(f);
  u = (u + 0x7FFFu + ((u>>16)&1u)) >> 16;
  return (ushort)u;
}
static __device__ __forceinline__ float bf2f(ushort h){ return __uint_as_float(((unsigned)h)<<16); }
// exact-ish 3-way split: v == h + m + l to within 2^-26 relative
static __device__ __forceinline__ void split3(float v, ushort* h, ushort* m, ushort* l){
  ushort hh = f2bf(v);
  float r1 = v - bf2f(hh);
  ushort mm = f2bf(r1);
  float r2 = r1 - bf2f(mm);
  *h = hh; *m = mm; *l = f2bf(r2);
}

// DPP lane-swap adds for sum over 8 consecutive lanes (lanes 8k..8k+7).
static __device__ __forceinline__ float dpp_add_xor1(float v){
  return v + __int_as_float(__builtin_amdgcn_mov_dpp(__float_as_int(v), 0xB1, 0xF, 0xF, true));
}
static __device__ __forceinline__ float dpp_add_xor2(float v){
  return v + __int_as_float(__builtin_amdgcn_mov_dpp(__float_as_int(v), 0x4E, 0xF, 0xF, true));
}
static __device__ __forceinline__ float dpp_add_hm(float v){
  return v + __int_as_float(__builtin_amdgcn_mov_dpp(__float_as_int(v), 0x141, 0xF, 0xF, true));
}

#define GLL(g, s) __builtin_amdgcn_global_load_lds( \
    (const __attribute__((address_space(1))) unsigned int*)(g), \
    (__attribute__((address_space(3))) unsigned int*)(s), 16, 0, 0)

// ================= bf16x6 MFMA GEMM (fp32-accurate via exact 3-way split) =================
// C[M,N] = act(A[M,K] @ W[N,K]^T + bias) (+C if accum)
// A,W pre-split into bf16 h/m/l. M mult of 128, K mult of 32, N masked.
// lda = row stride of the A split arrays in USHORTS (normally == K).
// grid: (ceil(N/128), M/128), 256 threads (4 waves, 2x2 of 64x64 wave tiles)
__global__ __launch_bounds__(256) void k_mgemm(
    const ushort* __restrict__ AH, const ushort* __restrict__ AM, const ushort* __restrict__ AL,
    const ushort* __restrict__ WH, const ushort* __restrict__ WM, const ushort* __restrict__ WL,
    const float* __restrict__ bias,
    float* __restrict__ outF, ushort* __restrict__ outH, ushort* __restrict__ outM, ushort* __restrict__ outL,
    int M, int N, int K, int lda, int act, int accum){
  __shared__ ushort sA0[128*32];
  __shared__ ushort sA1[128*32];
  __shared__ ushort sA2[128*32];
  __shared__ ushort sW0[128*32];
  __shared__ ushort sW1[128*32];
  __shared__ ushort sW2[128*32];
  int tid = threadIdx.x;
  int wid = tid>>6, lane = tid&63;
  int quad = lane>>4, col = lane&15;
  int m0 = blockIdx.y*128, n0 = blockIdx.x*128;
  int wm = (wid&1)*64, wn = (wid>>1)*64;
  v4f acc[4][4];
  #pragma unroll
  for (int i=0;i<4;i++)
    #pragma unroll
    for (int j=0;j<4;j++) acc[i][j] = (v4f)(0.f);

  // DMA staging: wave wid stages LDS rows [32*wid, 32*wid+32) of each array
  int rl = lane>>2, kc8 = (lane&3)<<3;
  size_t aoff0 = (size_t)(m0 + 32*wid + rl)*lda + kc8;
  size_t aoff1 = aoff0 + (size_t)16*lda;
  int wr0 = n0 + 32*wid + rl;      if (wr0 > N-1) wr0 = N-1;
  int wr1 = n0 + 32*wid + 16 + rl; if (wr1 > N-1) wr1 = N-1;
  size_t woff0 = (size_t)wr0*K + kc8;
  size_t woff1 = (size_t)wr1*K + kc8;
  int sb0 = wid*1024, sb1 = wid*1024 + 512;   // ushort indices

  for (int kb = 0; kb < K; kb += 32) {
    GLL(AH+aoff0+kb, &sA0[sb0]); GLL(AH+aoff1+kb, &sA0[sb1]);
    GLL(AM+aoff0+kb, &sA1[sb0]); GLL(AM+aoff1+kb, &sA1[sb1]);
    GLL(AL+aoff0+kb, &sA2[sb0]); GLL(AL+aoff1+kb, &sA2[sb1]);
    GLL(WH+woff0+kb, &sW0[sb0]); GLL(WH+woff1+kb, &sW0[sb1]);
    GLL(WM+woff0+kb, &sW1[sb0]); GLL(WM+woff1+kb, &sW1[sb1]);
    GLL(WL+woff0+kb, &sW2[sb0]); GLL(WL+woff1+kb, &sW2[sb1]);
    __syncthreads();
    v8s af[3][4];
    #pragma unroll
    for (int i=0;i<4;i++){
      int ro = (wm+16*i+col)*32 + quad*8;
      af[0][i] = *(const v8s*)&sA0[ro];
      af[1][i] = *(const v8s*)&sA1[ro];
      af[2][i] = *(const v8s*)&sA2[ro];
    }
    #pragma unroll
    for (int j=0;j<4;j++){
      int ro = (wn+16*j+col)*32 + quad*8;
      v8s b0 = *(const v8s*)&sW0[ro];
      v8s b1 = *(const v8s*)&sW1[ro];
      v8s b2 = *(const v8s*)&sW2[ro];
      #pragma unroll
      for (int i=0;i<4;i++){
        // smallest-first accumulate; dropped terms <= 2^-26
        acc[i][j] = __builtin_amdgcn_mfma_f32_16x16x32_bf16(af[2][i], b0, acc[i][j], 0,0,0); // al*bh
        acc[i][j] = __builtin_amdgcn_mfma_f32_16x16x32_bf16(af[1][i], b1, acc[i][j], 0,0,0); // am*bm
        acc[i][j] = __builtin_amdgcn_mfma_f32_16x16x32_bf16(af[0][i], b2, acc[i][j], 0,0,0); // ah*bl
        acc[i][j] = __builtin_amdgcn_mfma_f32_16x16x32_bf16(af[1][i], b0, acc[i][j], 0,0,0); // am*bh
        acc[i][j] = __builtin_amdgcn_mfma_f32_16x16x32_bf16(af[0][i], b1, acc[i][j], 0,0,0); // ah*bm
        acc[i][j] = __builtin_amdgcn_mfma_f32_16x16x32_bf16(af[0][i], b0, acc[i][j], 0,0,0); // ah*bh
      }
    }
    __syncthreads();
  }
  // epilogue: C/D layout col=lane&15, row=quad*4+reg
  #pragma unroll
  for (int i=0;i<4;i++){
    int mb = m0 + wm + 16*i + quad*4;
    #pragma unroll
    for (int j=0;j<4;j++){
      int n = n0 + wn + 16*j + col;
      if (n >= N) continue;
      float bv = bias ? bias[n] : 0.f;
      #pragma unroll
      for (int r=0;r<4;r++){
        float v = acc[i][j][r] + bv;
        if (act == 1) v = geluf_(v);
        else if (act == 2) v = tanhf(v);
        size_t off = (size_t)(mb+r)*N + n;
        if (accum) v += outF[off];
        if (outF) outF[off] = v;
        if (outH) split3(v, outH+off, outM+off, outL+off);
      }
    }
  }
}

// ================= fp32 GEMM (tiny: head1 only) =================
#define BM 128
#define BN 64
#define BKK 16
__global__ __launch_bounds__(256) void k_gemm(const float* __restrict__ A, const float* __restrict__ W,
    const float* __restrict__ bias, float* __restrict__ C, int M, int N, int K, int act, int accum){
  __shared__ float As[BKK][BM+4];
  __shared__ float Ws[BKK][BN+4];
  int tid = threadIdx.x;
  int m0 = blockIdx.y*BM, n0 = blockIdx.x*BN;
  int tx = tid & 15, ty = tid >> 4;
  float acc[8][4];
  #pragma unroll
  for (int i=0;i<8;i++)
    #pragma unroll
    for (int j=0;j<4;j++) acc[i][j]=0.f;
  for (int k0 = 0; k0 < K; k0 += BKK) {
    int r = tid >> 2, c4 = (tid & 3) << 2;
    #pragma unroll
    for (int hfl = 0; hfl < 2; hfl++) {
      int rr = r + hfl*64;
      float4 v = make_float4(0.f,0.f,0.f,0.f);
      if (m0 + rr < M && k0 + c4 < K)
        v = *(const float4*)(A + (size_t)(m0+rr)*K + k0 + c4);
      As[c4+0][rr]=v.x; As[c4+1][rr]=v.y; As[c4+2][rr]=v.z; As[c4+3][rr]=v.w;
    }
    {
      int n = tid >> 2;
      float4 v = make_float4(0.f,0.f,0.f,0.f);
      if (n0 + n < N && k0 + c4 < K)
        v = *(const float4*)(W + (size_t)(n0+n)*K + k0 + c4);
      Ws[c4+0][n]=v.x; Ws[c4+1][n]=v.y; Ws[c4+2][n]=v.z; Ws[c4+3][n]=v.w;
    }
    __syncthreads();
    #pragma unroll
    for (int kk = 0; kk < BKK; kk++) {
      float af[8], bf[4];
      float4 a0 = *(const float4*)&As[kk][ty*8];
      float4 a1 = *(const float4*)&As[kk][ty*8+4];
      af[0]=a0.x; af[1]=a0.y; af[2]=a0.z; af[3]=a0.w;
      af[4]=a1.x; af[5]=a1.y; af[6]=a1.z; af[7]=a1.w;
      float4 b0 = *(const float4*)&Ws[kk][tx*4];
      bf[0]=b0.x; bf[1]=b0.y; bf[2]=b0.z; bf[3]=b0.w;
      #pragma unroll
      for (int i=0;i<8;i++)
        #pragma unroll
        for (int j=0;j<4;j++) acc[i][j] = fmaf(af[i], bf[j], acc[i][j]);
    }
    __syncthreads();
  }
  #pragma unroll
  for (int i=0;i<8;i++){
    int m = m0 + ty*8 + i;
    if (m >= M) continue;
    #pragma unroll
    for (int j=0;j<4;j++){
      int n = n0 + tx*4 + j;
      if (n >= N) continue;
      float v = acc[i][j];
      if (bias) v += bias[n];
      if (act == 1) v = geluf_(v);
      else if (act == 2) v = tanhf(v);
      size_t off = (size_t)m*N + n;
      if (accum) v += C[off];
      C[off] = v;
    }
  }
}

// ================= splits =================
__global__ __launch_bounds__(256) void k_wsplit(const float* __restrict__ src, ushort* __restrict__ hi,
    ushort* __restrict__ mi, ushort* __restrict__ lo, int N, int K, int Kp){
  int idx = blockIdx.x*256 + threadIdx.x;
  if (idx >= N*Kp) return;
  int n = idx / Kp, k = idx - n*Kp;
  float v = (k < K) ? src[(size_t)n*K + k] : 0.f;
  split3(v, hi+idx, mi+idx, lo+idx);
}

__global__ __launch_bounds__(256) void k_split(const float* __restrict__ src, ushort* __restrict__ hi,
    ushort* __restrict__ mi, ushort* __restrict__ lo, int n){
  int idx = blockIdx.x*256 + threadIdx.x;
  if (idx >= n) return;
  split3(src[idx], hi+idx, mi+idx, lo+idx);
}

// transpose+pad+split one chunk of rows: rows [r0g, r0g+RC)
__global__ __launch_bounds__(256) void k_tsplit(const float* __restrict__ x, ushort* __restrict__ hi,
    ushort* __restrict__ mi, ushort* __restrict__ lo, int r0g){
  int idx = blockIdx.x*256 + threadIdx.x;
  if (idx >= RC*KCONV) return;
  int r = idx / KCONV, c = idx - r*KCONV;
  int gr = r0g + r;
  int b = gr / LL, l = gr - b*LL;
  float v = (c < NCH) ? x[((size_t)b*NCH + c)*LL + l] : 0.f;
  split3(v, hi+idx, mi+idx, lo+idx);
}

// ================= LayerNorm (D=320), optional add, outputs fp32 and/or bf16 h/m/l
__global__ __launch_bounds__(256) void k_ln(const float* __restrict__ A, const float* __restrict__ Badd,
    float* __restrict__ Of, ushort* __restrict__ Oh, ushort* __restrict__ Om, ushort* __restrict__ Ol,
    const float* __restrict__ w, const float* __restrict__ b, int nrows){
  int wid = threadIdx.x >> 6, lane = threadIdx.x & 63;
  int row = blockIdx.x*4 + wid;
  if (row >= nrows) return;
  const float* a = A + (size_t)row*DM;
  float x[5]; float s = 0.f;
  #pragma unroll
  for (int j=0;j<5;j++){
    int c = lane + j*64;
    x[j] = a[c];
    if (Badd) x[j] += Badd[(size_t)row*DM + c];
    s += x[j];
  }
  #pragma unroll
  for (int m=1;m<64;m<<=1) s += __shfl_xor(s, m);
  float mean = s * (1.f/DM);
  float vs = 0.f;
  #pragma unroll
  for (int j=0;j<5;j++){ float d = x[j]-mean; vs += d*d; }
  #pragma unroll
  for (int m=1;m<64;m<<=1) vs += __shfl_xor(vs, m);
  float inv = rsqrtf(vs*(1.f/DM) + 1e-5f);
  #pragma unroll
  for (int j=0;j<5;j++){
    int c = lane + j*64;
    float v = (x[j]-mean)*inv*w[c] + b[c];
    size_t off = (size_t)row*DM + c;
    if (Of) Of[off] = v;
    if (Oh) split3(v, Oh+off, Om+off, Ol+off);
  }
}

// fused double-LN: O = LN(LN(A+F)*w2+b2)*w3+b3
__global__ __launch_bounds__(256) void k_ln2x(const float* __restrict__ A, const float* __restrict__ F,
    const float* __restrict__ w2, const float* __restrict__ b2,
    const float* __restrict__ w3, const float* __restrict__ b3,
    float* __restrict__ O, int nrows){
  int wid = threadIdx.x >> 6, lane = threadIdx.x & 63;
  int row = blockIdx.x*4 + wid;
  if (row >= nrows) return;
  float x[5]; float s = 0.f;
  #pragma unroll
  for (int j=0;j<5;j++){
    int c = lane + j*64;
    x[j] = A[(size_t)row*DM + c] + F[(size_t)row*DM + c];
    s += x[j];
  }
  #pragma unroll
  for (int m=1;m<64;m<<=1) s += __shfl_xor(s, m);
  float mean = s * (1.f/DM);
  float vs = 0.f;
  #pragma unroll
  for (int j=0;j<5;j++){ float d = x[j]-mean; vs += d*d; }
  #pragma unroll
  for (int m=1;m<64;m<<=1) vs += __shfl_xor(vs, m);
  float inv = rsqrtf(vs*(1.f/DM) + 1e-5f);
  float s2 = 0.f;
  #pragma unroll
  for (int j=0;j<5;j++){
    int c = lane + j*64;
    x[j] = (x[j]-mean)*inv*w2[c] + b2[c];
    s2 += x[j];
  }
  #pragma unroll
  for (int m=1;m<64;m<<=1) s2 += __shfl_xor(s2, m);
  float mean2 = s2 * (1.f/DM);
  float vs2 = 0.f;
  #pragma unroll
  for (int j=0;j<5;j++){ float d = x[j]-mean2; vs2 += d*d; }
  #pragma unroll
  for (int m=1;m<64;m<<=1) vs2 += __shfl_xor(vs2, m);
  float inv2 = rsqrtf(vs2*(1.f/DM) + 1e-5f);
  #pragma unroll
  for (int j=0;j<5;j++){
    int c = lane + j*64;
    O[(size_t)row*DM + c] = (x[j]-mean2)*inv2*w3[c] + b3[c];
  }
}

// ================= attention pass 1: per (b,h), online softmax -> o (h/m/l), store (m,l)
__global__ __launch_bounds__(256) void k_attn1(const float* __restrict__ qkv,
    ushort* __restrict__ oh, ushort* __restrict__ om, ushort* __restrict__ ol, float* __restrict__ ml){
  __shared__ float Ks[LL*HD];
  __shared__ float Vs[LL*HD];
  int b = blockIdx.x >> 4, h = blockIdx.x & 15;
  int tid = threadIdx.x;
  for (int idx = tid; idx < LL*HD; idx += 256) {
    int r = idx / HD, c = idx - r*HD;
    const float* base = qkv + (size_t)(b*LL+r)*960 + h*HD + c;
    Ks[idx] = base[320];
    Vs[idx] = base[640];
  }
  __syncthreads();
  int q = tid;
  if (q >= LL) return;
  const float* qp = qkv + (size_t)(b*LL+q)*960 + h*HD;
  float qr[HD];
  #pragma unroll
  for (int d4 = 0; d4 < 5; d4++) {
    float4 v = *(const float4*)(qp + d4*4);
    qr[d4*4]=v.x; qr[d4*4+1]=v.y; qr[d4*4+2]=v.z; qr[d4*4+3]=v.w;
  }
  float m = -1e30f, l = 0.f;
  float o[HD];
  #pragma unroll
  for (int d=0; d<HD; d++) o[d]=0.f;
  for (int k = 0; k < LL; k++) {
    float s = 0.f;
    #pragma unroll
    for (int d = 0; d < HD; d++) s = fmaf(qr[d], Ks[k*HD+d], s);
    s *= ATTN_SCALE;
    float nm = fmaxf(m, s);
    float al = __expf(m - nm);
    float p  = __expf(s - nm);
    l = l*al + p;
    #pragma unroll
    for (int d = 0; d < HD; d++) o[d] = fmaf(p, Vs[k*HD+d], o[d]*al);
    m = nm;
  }
  float inv = 1.f/l;
  size_t ob = (size_t)(b*LL+q)*DM + h*HD;
  #pragma unroll
  for (int d = 0; d < HD; d++) {
    split3(o[d]*inv, oh+ob+d, om+ob+d, ol+ob+d);
  }
  size_t mlb = ((size_t)(b*NH+h)*LL + q)*2;
  ml[mlb+0] = m;
  ml[mlb+1] = l;
}

// ================= attention pass 2: head-mean probabilities, tiled 32q x 32k
#define QS 164
__global__ __launch_bounds__(256) void k_attnmean(const float* __restrict__ qkv,
    const float* __restrict__ ml, float* __restrict__ outp){
  __shared__ float Qs[32*QS];
  __shared__ float Ksh[32*QS];
  __shared__ float Ms[NH*32];
  __shared__ float Ls[NH*32];
  int b = blockIdx.z;
  int q0 = blockIdx.y*32, k0 = blockIdx.x*32;
  int tid = threadIdx.x;
  for (int idx = tid; idx < NH*32; idx += 256) {
    int h = idx >> 5, r = idx & 31;
    int q = q0 + r;
    float m = 0.f, li = 1.f;
    if (q < LL) {
      size_t base = ((size_t)(b*NH+h)*LL + q)*2;
      m = ml[base+0];
      li = 1.f/ml[base+1];
    }
    Ms[idx] = m; Ls[idx] = li;
  }
  int tx = tid & 31, ty = tid >> 5;
  float acc[4] = {0.f,0.f,0.f,0.f};
  for (int hc = 0; hc < 2; hc++) {
    __syncthreads();
    for (int idx = tid; idx < 32*160; idx += 256) {
      int r = idx / 160, c = idx - r*160;
      int q = q0 + r, k = k0 + r;
      Qs[r*QS + c]  = (q < LL) ? qkv[(size_t)(b*LL+q)*960 + hc*160 + c] : 0.f;
      Ksh[r*QS + c] = (k < LL) ? qkv[(size_t)(b*LL+k)*960 + 320 + hc*160 + c] : 0.f;
    }
    __syncthreads();
    #pragma unroll
    for (int hh = 0; hh < 8; hh++) {
      int h = hc*8 + hh;
      float kf[HD];
      #pragma unroll
      for (int d4 = 0; d4 < 5; d4++) {
        float4 v = *(const float4*)&Ksh[tx*QS + hh*HD + d4*4];
        kf[d4*4]=v.x; kf[d4*4+1]=v.y; kf[d4*4+2]=v.z; kf[d4*4+3]=v.w;
      }
      #pragma unroll
      for (int j = 0; j < 4; j++) {
        int qr = ty + j*8;
        float s = 0.f;
        #pragma unroll
        for (int d4 = 0; d4 < 5; d4++) {
          float4 v = *(const float4*)&Qs[qr*QS + hh*HD + d4*4];
          s += v.x*kf[d4*4] + v.y*kf[d4*4+1] + v.z*kf[d4*4+2] + v.w*kf[d4*4+3];
        }
        acc[j] += __expf(s*ATTN_SCALE - Ms[h*32 + qr]) * Ls[h*32 + qr];
      }
    }
  }
  #pragma unroll
  for (int j = 0; j < 4; j++) {
    int q = q0 + ty + j*8, k = k0 + tx;
    if (q < LL && k < LL)
      outp[(size_t)(b*LL+q)*LL + k] = acc[j] * (1.f/NH);
  }
}

// ================= selective scan v4: all-LDS loop (x-conv, BC-conv, dt/dA staged; y via LDS)
// two 100-step halves to fit 40KB LDS; zero global ops inside the recurrence loop.
#define HT 100
__global__ __launch_bounds__(256) void k_scan(const float* __restrict__ big,
    const float* __restrict__ cw, const float* __restrict__ cb,
    const float* __restrict__ dtb, const float* __restrict__ alog, const float* __restrict__ Dp,
    float* __restrict__ y){
  __shared__ float xs[HT*PP];     // 12.8 KB: x-conv result, then y in-place
  __shared__ float bc[HT*64];     // 25.6 KB: B (0..31) and C (32..63) per row
  __shared__ float2 dd[LL];       // 1.6 KB: (dA_t, dt_t), full length
  int b = blockIdx.x / HM, h = blockIdx.x - (blockIdx.x/HM)*HM;
  int tid = threadIdx.x;
  float aexp = __expf(alog[h]);
  float dtbh = dtb[h];
  for (int idx = tid; idx < LL; idx += 256) {
    float raw = big[(size_t)(b*LL+idx)*DPROJ + 1344 + h] + dtbh;
    float sp = (raw > 30.f) ? raw : log1pf(__expf(raw));
    dd[idx] = make_float2(__expf(-aexp * sp), sp);
  }
  int p = tid >> 3, ng = tid & 7, n0 = ng*4;
  float st0=0.f, st1=0.f, st2=0.f, st3=0.f;
  float Dh = Dp[h];
  for (int half = 0; half < 2; half++) {
    int t0 = half*HT;
    __syncthreads();   // half 0: dd visible; half 1: prior reads done before overwrite
    // stage x channels (conv+silu) for rows t0..t0+HT-1
    for (int idx = tid; idx < HT*PP; idx += 256) {
      int r = idx >> 5, c = idx & 31;
      int gr = t0 + r;
      int ch = h*PP + c;
      float acc = cb[ch];
      #pragma unroll
      for (int k = 0; k < 4; k++) {
        int li = gr - 3 + k;
        if (li >= 0) acc = fmaf(big[(size_t)(b*LL+li)*DPROJ + 640 + ch], cw[ch*4+k], acc);
      }
      xs[idx] = acc * sigmoidf_(acc);
    }
    // stage B/C channels (conv+silu) for rows t0..t0+HT-1 (xBC channels 640..703)
    for (int idx = tid; idx < HT*64; idx += 256) {
      int r = idx >> 6, j = idx & 63;
      int gr = t0 + r;
      int ch = 640 + j;
      float acc = cb[ch];
      #pragma unroll
      for (int k = 0; k < 4; k++) {
        int li = gr - 3 + k;
        if (li >= 0) acc = fmaf(big[(size_t)(b*LL+li)*DPROJ + 1280 + j], cw[ch*4+k], acc);
      }
      bc[idx] = acc * sigmoidf_(acc);
    }
    __syncthreads();
    float4 Bc = *(const float4*)&bc[n0];
    float4 Cc = *(const float4*)&bc[32 + n0];
    float  xv = xs[p];
    float2 ddc = dd[t0];
    for (int tt = 0; tt < HT; tt++) {
      float4 Bn = Bc, Cn = Cc;
      float  xn = xv;
      float2 ddn = ddc;
      if (tt < HT-1) {
        Bn  = *(const float4*)&bc[(tt+1)*64 + n0];
        Cn  = *(const float4*)&bc[(tt+1)*64 + 32 + n0];
        xn  = xs[(tt+1)*PP + p];
        ddn = dd[t0+tt+1];
      }
      float dav = ddc.x, dtv = ddc.y;
      float coef = dtv * xv;
      st0 = fmaf(coef, Bc.x, st0*dav);
      st1 = fmaf(coef, Bc.y, st1*dav);
      st2 = fmaf(coef, Bc.z, st2*dav);
      st3 = fmaf(coef, Bc.w, st3*dav);
      float part = st0*Cc.x + st1*Cc.y + st2*Cc.z + st3*Cc.w;
      part = dpp_add_xor1(part);
      part = dpp_add_xor2(part);
      part = dpp_add_hm(part);
      if (ng == 0) xs[tt*PP + p] = part + Dh*xv;   // y into dead xs slot (last read was tt-1)
      Bc = Bn; Cc = Cn; xv = xn; ddc = ddn;
    }
    __syncthreads();
    // bulk coalesced store of y rows t0..t0+HT-1
    for (int idx = tid; idx < HT*PP; idx += 256) {
      int r = idx >> 5, c = idx & 31;
      y[(size_t)(b*LL + t0 + r)*DIN + h*PP + c] = xs[idx];
    }
  }
}

// ================= mamba epilogue: gate + rmsnorm; writes h/m/l IN-PLACE into BIG cols 0..959
__global__ __launch_bounds__(256) void k_mpost(const float* __restrict__ yc, float* __restrict__ big,
    const float* __restrict__ gw, int nrows){
  int wid = threadIdx.x >> 6, lane = threadIdx.x & 63;
  int row = blockIdx.x*4 + wid;
  if (row >= nrows) return;
  float v[10]; float ss = 0.f;
  #pragma unroll
  for (int j = 0; j < 10; j++) {
    int c = lane + j*64;
    float ys = yc[(size_t)row*DIN + c];                 // already includes D-skip
    float z  = big[(size_t)row*DPROJ + c];
    float val = ys * (z * sigmoidf_(z));
    v[j] = val; ss += val*val;
  }
  #pragma unroll
  for (int m=1;m<64;m<<=1) ss += __shfl_xor(ss, m);
  float scale = rsqrtf(ss*(1.f/DIN) + 1e-5f);
  ushort* rowp = (ushort*)(big + (size_t)row*DPROJ);    // z/xBC cols are dead now
  #pragma unroll
  for (int j = 0; j < 10; j++) {
    int c = lane + j*64;
    float val = v[j]*scale*gw[c];
    split3(val, rowp+c, rowp+640+c, rowp+1280+c);
  }
}

// ================= pool2
__global__ __launch_bounds__(256) void k_pool2(const float* __restrict__ A, const float* __restrict__ w2,
    const float* __restrict__ b2, float* __restrict__ out, int nrows){
  int row = blockIdx.x*256 + threadIdx.x;
  if (row >= nrows) return;
  float s = b2[0];
  const float* a = A + (size_t)row*80;
  #pragma unroll
  for (int j = 0; j < 80; j++) s = fmaf(a[j], w2[j], s);
  out[row] = s;
}

// ================= softmax over L + attention-pool
__global__ __launch_bounds__(256) void k_pool(const float* __restrict__ logits, const float* __restrict__ h,
    float* __restrict__ a_out, float* __restrict__ pooled){
  __shared__ float red[256];
  __shared__ float as_[LL];
  int b = blockIdx.x, tid = threadIdx.x;
  float v = (tid < LL) ? logits[b*LL + tid] : -1e30f;
  red[tid] = v; __syncthreads();
  for (int s=128; s>0; s>>=1){ if (tid<s) red[tid]=fmaxf(red[tid],red[tid+s]); __syncthreads(); }
  float mx = red[0]; __syncthreads();
  float e = (tid<LL) ? __expf(v - mx) : 0.f;
  red[tid] = e; __syncthreads();
  for (int s=128; s>0; s>>=1){ if (tid<s) red[tid]+=red[tid+s]; __syncthreads(); }
  float inv = 1.f/red[0];
  if (tid < LL){ float av = e*inv; as_[tid]=av; a_out[b*LL+tid]=av; }
  __syncthreads();
  for (int d = tid; d < DM; d += 256) {
    float s = 0.f;
    for (int l=0;l<LL;l++) s = fmaf(h[(size_t)(b*LL+l)*DM + d], as_[l], s);
    pooled[b*DM + d] = s;
  }
}

// ================= head final dot
__global__ __launch_bounds__(128) void k_head2(const float* __restrict__ hr, const float* __restrict__ w2,
    const float* __restrict__ b2, float* __restrict__ out){
  int b = threadIdx.x;
  if (b >= BB) return;
  float s = b2[0];
  const float* a = hr + (size_t)b*160;
  #pragma unroll
  for (int j = 0; j < 160; j++) s = fmaf(a[j], w2[j], s);
  out[b] = s;
}

// ================= host side =================
static inline void mgemm(const ushort* AH, const ushort* AM, const ushort* AL,
    const ushort* WH, const ushort* WM, const ushort* WL,
    const float* bias, float* outF, ushort* outH, ushort* outM, ushort* outL,
    int M, int N, int K, int lda, int act, int accum, hipStream_t s){
  hipLaunchKernelGGL(k_mgemm, dim3((N+127)/128, M/128), dim3(256), 0, s,
                     AH, AM, AL, WH, WM, WL, bias, outF, outH, outM, outL, M, N, K, lda, act, accum);
}
static inline void wsplit(const float* src, ushort* hi, ushort* mi, ushort* lo, int N, int K, int Kp, hipStream_t s){
  hipLaunchKernelGGL(k_wsplit, dim3((N*Kp+255)/256), dim3(256), 0, s, src, hi, mi, lo, N, K, Kp);
}

// ---- workspace layout (float offsets), total 30,161,920 fl = 120.6 MB ----
#define F_WCONVH ((size_t)8192000)
#define F_WCONVM ((size_t)8217600)
#define F_WCONVL ((size_t)8243200)
#define F_WQKVH  ((size_t)8268800)
#define F_WQKVM  ((size_t)8422400)
#define F_WQKVL  ((size_t)8576000)
#define F_WOUTH  ((size_t)8729600)
#define F_WOUTM  ((size_t)8780800)
#define F_WOUTL  ((size_t)8832000)
#define F_WFF1H  ((size_t)8883200)
#define F_WFF1M  ((size_t)8985600)
#define F_WFF1L  ((size_t)9088000)
#define F_WFF2H  ((size_t)9190400)
#define F_WFF2M  ((size_t)9292800)
#define F_WFF2L  ((size_t)9395200)
#define F_WINH   ((size_t)9497600)
#define F_WINM   ((size_t)10370560)
#define F_WINL   ((size_t)11243520)
#define F_WMOH   ((size_t)12116480)
#define F_WMOM   ((size_t)12526080)
#define F_WMOL   ((size_t)12935680)
#define F_WPQH   ((size_t)13345280)
#define F_WPQM   ((size_t)13498880)
#define F_WPQL   ((size_t)13652480)
#define F_WPOH   ((size_t)13806080)
#define F_WPOM   ((size_t)13857280)
#define F_WPOL   ((size_t)13908480)
#define F_WPLH   ((size_t)13959680)
#define F_WPLM   ((size_t)13972480)
#define F_WPLL   ((size_t)13985280)
#define SB       ((size_t)13998080)
// phase A/C scratch (CH=32, RC=6400)
#define S_XTH  (SB+0)
#define S_XTM  (SB+512000)
#define S_XTL  (SB+1024000)
#define S_HH   (SB+1536000)
#define S_HM   (SB+2560000)
#define S_HL   (SB+3584000)
#define S_TH   (SB+4608000)
#define S_TM   (SB+5632000)
#define S_TL   (SB+6656000)
#define S_QKV  (SB+7680000)        // 6,144,000 fp32
#define S_FF1H (SB+7680000)        // overlays QKV (dead after attnmean)
#define S_FF1M (SB+9728000)
#define S_FF1L (SB+11776000)
#define S_P1   (SB+7680000)        // phase C overlay of QKV
#define S_ML   (SB+13824000)
#define S_DEST (SB+14028800)       // 2,048,000 -> ends 16,076,800
#define S_LOG  (SB+16076800)
#define S_PL   (SB+16102400)
#define S_HR   (SB+16143360)       // ends 16,163,840
// phase B overlay (CH=32, RC=6400): MT, BIG, YC
#define B_MTH  (SB+0)              // 1,024,000 each
#define B_MTM  (SB+1024000)
#define B_MTL  (SB+2048000)
#define B_BIG  (SB+3072000)        // 8,729,600 -> ends 11,801,600
#define B_YC   (SB+11801600)       // 4,096,000 -> ends 15,897,600

// output layout (floats): (out, sp_attn, post_attn, a)
#define O_OUT ((size_t)0)
#define O_A1  ((size_t)128)
#define O_A2  ((size_t)5120128)
#define O_A   ((size_t)10240128)

extern "C" void kernel_launch(void* const* d_in, const int* in_sizes, int n_in,
                              void* d_out, int out_size, void* d_ws, size_t ws_size,
                              hipStream_t stream) {
  const float* x         = (const float*)d_in[0];
  const float* sp_conv_w = (const float*)d_in[1];
  const float* sp_conv_b = (const float*)d_in[2];
  const float* sp_qkv_w  = (const float*)d_in[3];
  const float* sp_qkv_b  = (const float*)d_in[4];
  const float* sp_out_w  = (const float*)d_in[5];
  const float* sp_out_b  = (const float*)d_in[6];
  const float* sp_ln1_w  = (const float*)d_in[7];
  const float* sp_ln1_b  = (const float*)d_in[8];
  const float* sp_ff1_w  = (const float*)d_in[9];
  const float* sp_ff1_b  = (const float*)d_in[10];
  const float* sp_ff2_w  = (const float*)d_in[11];
  const float* sp_ff2_b  = (const float*)d_in[12];
  const float* sp_ln2_w  = (const float*)d_in[13];
  const float* sp_ln2_b  = (const float*)d_in[14];
  const float* norm_in_w = (const float*)d_in[15];
  const float* norm_in_b = (const float*)d_in[16];
  const float* m_in_w    = (const float*)d_in[17];
  const float* m_conv_w  = (const float*)d_in[18];
  const float* m_conv_b  = (const float*)d_in[19];
  const float* m_dt_bias = (const float*)d_in[20];
  const float* m_A_log   = (const float*)d_in[21];
  const float* m_D       = (const float*)d_in[22];
  const float* m_gnorm_w = (const float*)d_in[23];
  const float* m_out_w   = (const float*)d_in[24];
  const float* ln_w      = (const float*)d_in[25];
  const float* ln_b      = (const float*)d_in[26];
  const float* pm_qkv_w  = (const float*)d_in[27];
  const float* pm_qkv_b  = (const float*)d_in[28];
  const float* pm_out_w  = (const float*)d_in[29];
  const float* pm_out_b  = (const float*)d_in[30];
  const float* pm_ln_w   = (const float*)d_in[31];
  const float* pm_ln_b   = (const float*)d_in[32];
  const float* pool_w1   = (const float*)d_in[33];
  const float* pool_b1   = (const float*)d_in[34];
  const float* pool_w2   = (const float*)d_in[35];
  const float* pool_b2   = (const float*)d_in[36];
  const float* head_w1   = (const float*)d_in[37];
  const float* head_b1   = (const float*)d_in[38];
  const float* head_w2   = (const float*)d_in[39];
  const float* head_b2   = (const float*)d_in[40];

  float* ws  = (float*)d_ws;
  float* H   = ws;                 // F_H = 0, 8,192,000 fl persistent
  float* out = (float*)d_out;

  #define U(off) ((ushort*)(ws + (off)))

  // ---- phase 0: weight splits ----
  wsplit(sp_conv_w, U(F_WCONVH), U(F_WCONVM), U(F_WCONVL), DM, NCH, KCONV, stream);
  wsplit(sp_qkv_w,  U(F_WQKVH),  U(F_WQKVM),  U(F_WQKVL),  3*DM, DM, DM, stream);
  wsplit(sp_out_w,  U(F_WOUTH),  U(F_WOUTM),  U(F_WOUTL),  DM, DM, DM, stream);
  wsplit(sp_ff1_w,  U(F_WFF1H),  U(F_WFF1M),  U(F_WFF1L),  DIN, DM, DM, stream);
  wsplit(sp_ff2_w,  U(F_WFF2H),  U(F_WFF2M),  U(F_WFF2L),  DM, DIN, DIN, stream);
  for (int i = 0; i < 4; i++) {
    size_t wo = (size_t)i*DPROJ*DM;
    wsplit(m_in_w + wo, U(F_WINH)+wo, U(F_WINM)+wo, U(F_WINL)+wo, DPROJ, DM, DM, stream);
    size_t wo2 = (size_t)i*DM*DIN;
    wsplit(m_out_w + wo2, U(F_WMOH)+wo2, U(F_WMOM)+wo2, U(F_WMOL)+wo2, DM, DIN, DIN, stream);
  }
  wsplit(pm_qkv_w, U(F_WPQH), U(F_WPQM), U(F_WPQL), 3*DM, DM, DM, stream);
  wsplit(pm_out_w, U(F_WPOH), U(F_WPOM), U(F_WPOL), DM, DM, DM, stream);
  wsplit(pool_w1,  U(F_WPLH), U(F_WPLM), U(F_WPLL), 80, DM, DM, stream);

  // ---- phase A: input proj + spatial MHA + FF (per chunk of 32 seqs) ----
  for (int c = 0; c < NCHUNK; c++) {
    float* Hc = H + (size_t)c*RC*DM;
    hipLaunchKernelGGL(k_tsplit, dim3((RC*KCONV+255)/256), dim3(256), 0, stream, x,
                       U(S_XTH), U(S_XTM), U(S_XTL), c*RC);
    mgemm(U(S_XTH), U(S_XTM), U(S_XTL), U(F_WCONVH), U(F_WCONVM), U(F_WCONVL), sp_conv_b,
          Hc, U(S_HH), U(S_HM), U(S_HL), RC, DM, KCONV, KCONV, 0, 0, stream);
    mgemm(U(S_HH), U(S_HM), U(S_HL), U(F_WQKVH), U(F_WQKVM), U(F_WQKVL), sp_qkv_b,
          ws + S_QKV, nullptr, nullptr, nullptr, RC, 3*DM, DM, DM, 0, 0, stream);
    hipLaunchKernelGGL(k_attn1, dim3(CH*NH), dim3(256), 0, stream, ws + S_QKV,
                       U(S_TH), U(S_TM), U(S_TL), ws + S_ML);
    hipLaunchKernelGGL(k_attnmean, dim3(7,7,CH), dim3(256), 0, stream, ws + S_QKV,
                       ws + S_ML, out + O_A1 + (size_t)c*RC*LL);
    mgemm(U(S_TH), U(S_TM), U(S_TL), U(F_WOUTH), U(F_WOUTM), U(F_WOUTL), sp_out_b,
          ws + S_DEST, nullptr, nullptr, nullptr, RC, DM, DM, DM, 0, 0, stream);
    hipLaunchKernelGGL(k_ln, dim3(RC/4), dim3(256), 0, stream, Hc, ws + S_DEST,
                       Hc, U(S_HH), U(S_HM), U(S_HL), sp_ln1_w, sp_ln1_b, RC);
    mgemm(U(S_HH), U(S_HM), U(S_HL), U(F_WFF1H), U(F_WFF1M), U(F_WFF1L), sp_ff1_b,
          nullptr, U(S_FF1H), U(S_FF1M), U(S_FF1L), RC, DIN, DM, DM, 1, 0, stream);
    mgemm(U(S_FF1H), U(S_FF1M), U(S_FF1L), U(F_WFF2H), U(F_WFF2M), U(F_WFF2L), sp_ff2_b,
          ws + S_DEST, nullptr, nullptr, nullptr, RC, DM, DIN, DIN, 0, 0, stream);
    hipLaunchKernelGGL(k_ln2x, dim3(RC/4), dim3(256), 0, stream, Hc, ws + S_DEST,
                       sp_ln2_w, sp_ln2_b, norm_in_w, norm_in_b, Hc, RC);
  }

  // ---- phase B: mamba layers (per layer per chunk of 32 seqs) ----
  for (int i = 0; i < 4; i++) {
    const ushort* WIH = U(F_WINH) + (size_t)i*DPROJ*DM;
    const ushort* WIM = U(F_WINM) + (size_t)i*DPROJ*DM;
    const ushort* WIL = U(F_WINL) + (size_t)i*DPROJ*DM;
    const ushort* WOH = U(F_WMOH) + (size_t)i*DM*DIN;
    const ushort* WOM = U(F_WMOM) + (size_t)i*DM*DIN;
    const ushort* WOL = U(F_WMOL) + (size_t)i*DM*DIN;
    const float* cwi = m_conv_w + (size_t)i*CDIM*4;
    const float* cbi = m_conv_b + (size_t)i*CDIM;
    for (int c = 0; c < NCHUNK; c++) {
      float* Hc = H + (size_t)c*RC*DM;
      float* BIG = ws + B_BIG;
      hipLaunchKernelGGL(k_ln, dim3(RC/4), dim3(256), 0, stream, Hc, (const float*)nullptr,
                         (float*)nullptr, U(B_MTH), U(B_MTM), U(B_MTL),
                         ln_w + (size_t)i*DM, ln_b + (size_t)i*DM, RC);
      mgemm(U(B_MTH), U(B_MTM), U(B_MTL), WIH, WIM, WIL, nullptr,
            BIG, nullptr, nullptr, nullptr, RC, DPROJ, DM, DM, 0, 0, stream);
      hipLaunchKernelGGL(k_scan, dim3(CH*HM), dim3(256), 0, stream, BIG,
                         cwi, cbi, m_dt_bias + (size_t)i*HM, m_A_log + (size_t)i*HM,
                         m_D + (size_t)i*HM, ws + B_YC);
      hipLaunchKernelGGL(k_mpost, dim3(RC/4), dim3(256), 0, stream, ws + B_YC, BIG,
                         m_gnorm_w + (size_t)i*DIN, RC);
      // out-proj reads h/m/l embedded in BIG rows (cols 0/640/1280 us), lda = DPROJ*2 ushorts
      mgemm((const ushort*)BIG, (const ushort*)BIG + 640, (const ushort*)BIG + 1280,
            WOH, WOM, WOL, nullptr, Hc, nullptr, nullptr, nullptr,
            RC, DM, DIN, DPROJ*2, 0, 1, stream);
    }
  }

  // ---- phase C: post MHA + pooling prep (per chunk of 32 seqs) ----
  for (int c = 0; c < NCHUNK; c++) {
    float* Hc = H + (size_t)c*RC*DM;
    hipLaunchKernelGGL(k_split, dim3((RC*DM+255)/256), dim3(256), 0, stream, Hc,
                       U(S_HH), U(S_HM), U(S_HL), RC*DM);
    mgemm(U(S_HH), U(S_HM), U(S_HL), U(F_WPQH), U(F_WPQM), U(F_WPQL), pm_qkv_b,
          ws + S_QKV, nullptr, nullptr, nullptr, RC, 3*DM, DM, DM, 0, 0, stream);
    hipLaunchKernelGGL(k_attn1, dim3(CH*NH), dim3(256), 0, stream, ws + S_QKV,
                       U(S_TH), U(S_TM), U(S_TL), ws + S_ML);
    hipLaunchKernelGGL(k_attnmean, dim3(7,7,CH), dim3(256), 0, stream, ws + S_QKV,
                       ws + S_ML, out + O_A2 + (size_t)c*RC*LL);
    mgemm(U(S_TH), U(S_TM), U(S_TL), U(F_WPOH), U(F_WPOM), U(F_WPOL), pm_out_b,
          ws + S_DEST, nullptr, nullptr, nullptr, RC, DM, DM, DM, 0, 0, stream);
    hipLaunchKernelGGL(k_ln, dim3(RC/4), dim3(256), 0, stream, Hc, ws + S_DEST,
                       Hc, U(S_HH), U(S_HM), U(S_HL), pm_ln_w, pm_ln_b, RC);
    mgemm(U(S_HH), U(S_HM), U(S_HL), U(F_WPLH), U(F_WPLM), U(F_WPLL), pool_b1,
          ws + S_P1, nullptr, nullptr, nullptr, RC, 80, DM, DM, 2, 0, stream);
    hipLaunchKernelGGL(k_pool2, dim3((RC+255)/256), dim3(256), 0, stream, ws + S_P1, pool_w2, pool_b2,
                       ws + S_LOG + (size_t)c*RC, RC);
  }

  // ---- phase D: pooling + head ----
  hipLaunchKernelGGL(k_pool, dim3(BB), dim3(256), 0, stream, ws + S_LOG, H, out + O_A, ws + S_PL);
  hipLaunchKernelGGL(k_gemm, dim3((160+BN-1)/BN, (BB+BM-1)/BM), dim3(256), 0, stream,
                     ws + S_PL, head_w1, head_b1, ws + S_HR, BB, 160, DM, 1, 0);
  hipLaunchKernelGGL(k_head2, dim3(1), dim3(128), 0, stream, ws + S_HR, head_w2, head_b2, out + O_OUT);
}